// Round 1
// baseline (933.618 us; speedup 1.0000x reference)
//
#include <hip/hip_runtime.h>
#include <cstddef>

#define NN 100000
#define NE 800000
#define DIN 128
#define HID 96
#define DOUT 32
static constexpr float BN_EPS = 1e-5f;

// ---------------------------------------------------------------- setup kernels

__global__ void k_hist(const int* __restrict__ dst, int* __restrict__ deg) {
    int e = blockIdx.x * blockDim.x + threadIdx.x;
    if (e < NE) atomicAdd(&deg[dst[e]], 1);
}

__global__ void k_dinv(const int* __restrict__ deg, float* __restrict__ dinv) {
    int i = blockIdx.x * blockDim.x + threadIdx.x;
    if (i < NN) dinv[i] = rsqrtf((float)(deg[i] + 1));  // +1 self-loop, always > 0
}

// single-block exclusive scan of deg[0..NN) -> row_start[0..NN]
__global__ __launch_bounds__(1024) void k_scan(const int* __restrict__ deg,
                                               int* __restrict__ row_start) {
    __shared__ int lds[1024];
    const int PER = (NN + 1023) / 1024;  // 98
    int t = threadIdx.x;
    int base = t * PER;
    int end = base + PER; if (end > NN) end = NN; if (base > NN) base = NN;
    int s = 0;
    for (int i = base; i < end; ++i) s += deg[i];
    lds[t] = s;
    __syncthreads();
    for (int off = 1; off < 1024; off <<= 1) {
        int v = lds[t];
        int add = (t >= off) ? lds[t - off] : 0;
        __syncthreads();
        lds[t] = v + add;
        __syncthreads();
    }
    int excl = (t == 0) ? 0 : lds[t - 1];
    for (int i = base; i < end; ++i) { row_start[i] = excl; excl += deg[i]; }
    if (t == 1023) row_start[NN] = lds[1023];
}

__global__ void k_scatter(const int* __restrict__ src, const int* __restrict__ dst,
                          const int* __restrict__ row_start, int* __restrict__ cursor,
                          const float* __restrict__ dinv,
                          int* __restrict__ ssrc, float* __restrict__ swt) {
    int e = blockIdx.x * blockDim.x + threadIdx.x;
    if (e < NE) {
        int d = dst[e];
        int p = row_start[d] + atomicAdd(&cursor[d], 1);
        int s = src[e];
        ssrc[p] = s;
        swt[p] = dinv[s];
    }
}

// ---------------------------------------------------------------- GEMM (fp32 vector)
// Z[M x ND] = f(X)[M x KD] @ W[KD x ND], f = optional per-K-channel relu(a*x+c)
// tile: 64 rows x ND cols, K-chunk 32. block 256 = 16 col-threads x 16 row-threads.
template <int KD, int ND, bool FUSE>
__global__ __launch_bounds__(256) void k_gemm(const float* __restrict__ X,
                                              const float* __restrict__ W,
                                              float* __restrict__ Z,
                                              const float* __restrict__ bnA,
                                              const float* __restrict__ bnC, int M) {
    constexpr int BK = 32;
    constexpr int CT = 16;
    constexpr int CPT = ND / CT;   // 6 (ND=96) or 2 (ND=32)
    constexpr int RPT = 4;         // 16 row-threads * 4 = 64 rows
    __shared__ float Xs[64 * 33];  // +1 pad: row stride 33 breaks bank aliasing
    __shared__ float Ws[BK * ND];
    __shared__ float As[KD], Cs[KD];

    int tid = threadIdx.x;
    if (FUSE && tid < KD) { As[tid] = bnA[tid]; Cs[tid] = bnC[tid]; }
    int row0 = blockIdx.x * 64;
    int ct = tid % CT, rt = tid / CT;
    float acc[RPT][CPT];
#pragma unroll
    for (int r = 0; r < RPT; ++r)
#pragma unroll
        for (int c = 0; c < CPT; ++c) acc[r][c] = 0.f;

    for (int k0 = 0; k0 < KD; k0 += BK) {
        __syncthreads();
        // X tile 64x32, float4 per thread, 2 passes of 32 rows
#pragma unroll
        for (int pass = 0; pass < 2; ++pass) {
            int r = pass * 32 + (tid >> 3);
            int kq = (tid & 7) * 4;
            int grow = row0 + r;
            float4 v = make_float4(0.f, 0.f, 0.f, 0.f);
            if (grow < M) v = *(const float4*)&X[(size_t)grow * KD + k0 + kq];
            if (FUSE) {
                v.x = fmaxf(fmaf(As[k0 + kq + 0], v.x, Cs[k0 + kq + 0]), 0.f);
                v.y = fmaxf(fmaf(As[k0 + kq + 1], v.y, Cs[k0 + kq + 1]), 0.f);
                v.z = fmaxf(fmaf(As[k0 + kq + 2], v.z, Cs[k0 + kq + 2]), 0.f);
                v.w = fmaxf(fmaf(As[k0 + kq + 3], v.w, Cs[k0 + kq + 3]), 0.f);
            }
            Xs[r * 33 + kq + 0] = v.x;
            Xs[r * 33 + kq + 1] = v.y;
            Xs[r * 33 + kq + 2] = v.z;
            Xs[r * 33 + kq + 3] = v.w;
        }
        // W chunk 32 x ND
#pragma unroll
        for (int f = tid; f < BK * ND / 4; f += 256) {
            int kk = f / (ND / 4);
            int c4 = (f % (ND / 4)) * 4;
            *(float4*)&Ws[kk * ND + c4] = *(const float4*)&W[(size_t)(k0 + kk) * ND + c4];
        }
        __syncthreads();
#pragma unroll
        for (int kk = 0; kk < BK; ++kk) {
            float xr[RPT];
#pragma unroll
            for (int r = 0; r < RPT; ++r) xr[r] = Xs[(rt * RPT + r) * 33 + kk];
            float wc[CPT];
#pragma unroll
            for (int c = 0; c < CPT; ++c) wc[c] = Ws[kk * ND + ct * CPT + c];
#pragma unroll
            for (int r = 0; r < RPT; ++r)
#pragma unroll
                for (int c = 0; c < CPT; ++c) acc[r][c] = fmaf(xr[r], wc[c], acc[r][c]);
        }
    }
#pragma unroll
    for (int r = 0; r < RPT; ++r) {
        int grow = row0 + rt * RPT + r;
        if (grow < M) {
#pragma unroll
            for (int c = 0; c < CPT; ++c)
                Z[(size_t)grow * ND + ct * CPT + c] = acc[r][c];
        }
    }
}

// ---------------------------------------------------------------- aggregation, 96ch
// one wave per node: lane c holds ch c (and c+64 for lane<32). Fuses +bias and BN stats.
__global__ __launch_bounds__(256) void k_agg96(const float* __restrict__ Z,
                                               float* __restrict__ H,
                                               const float* __restrict__ bias,
                                               const int* __restrict__ row_start,
                                               const int* __restrict__ srcs,
                                               const float* __restrict__ wts,
                                               const float* __restrict__ dinv,
                                               float* __restrict__ gsum,
                                               float* __restrict__ gsq) {
    __shared__ float ssum[96], ssq[96];
    int tid = threadIdx.x;
    if (tid < 96) { ssum[tid] = 0.f; ssq[tid] = 0.f; }
    __syncthreads();
    int wid = tid >> 6, lane = tid & 63;
    int c0 = lane, c1 = 64 + lane;
    bool has1 = lane < 32;
    float b0 = bias[c0], b1v = has1 ? bias[c1] : 0.f;
    float lsum0 = 0.f, lsq0 = 0.f, lsum1 = 0.f, lsq1 = 0.f;
    int stride = gridDim.x * 4;
    for (int n = blockIdx.x * 4 + wid; n < NN; n += stride) {
        float dn = dinv[n];
        const float* zn = Z + (size_t)n * 96;
        float a0 = dn * zn[c0];
        float a1 = has1 ? dn * zn[c1] : 0.f;
        int e0 = row_start[n], e1 = row_start[n + 1];
        for (int e = e0; e < e1; ++e) {
            int s = srcs[e];
            float w = wts[e];
            const float* zs = Z + (size_t)s * 96;
            a0 = fmaf(w, zs[c0], a0);
            if (has1) a1 = fmaf(w, zs[c1], a1);
        }
        float h0 = fmaf(dn, a0, b0);
        H[(size_t)n * 96 + c0] = h0;
        lsum0 += h0; lsq0 = fmaf(h0, h0, lsq0);
        if (has1) {
            float h1 = fmaf(dn, a1, b1v);
            H[(size_t)n * 96 + c1] = h1;
            lsum1 += h1; lsq1 = fmaf(h1, h1, lsq1);
        }
    }
    atomicAdd(&ssum[c0], lsum0); atomicAdd(&ssq[c0], lsq0);
    if (has1) { atomicAdd(&ssum[c1], lsum1); atomicAdd(&ssq[c1], lsq1); }
    __syncthreads();
    if (tid < 96) { atomicAdd(&gsum[tid], ssum[tid]); atomicAdd(&gsq[tid], ssq[tid]); }
}

__global__ void k_bncoef(const float* __restrict__ gsum, const float* __restrict__ gsq,
                         const float* __restrict__ g, const float* __restrict__ be,
                         float* __restrict__ bnA, float* __restrict__ bnC) {
    int c = threadIdx.x;
    if (c < 96) {
        float mean = gsum[c] * (1.f / NN);
        float var = gsq[c] * (1.f / NN) - mean * mean;
        float inv = rsqrtf(var + BN_EPS);
        float a = g[c] * inv;
        bnA[c] = a;
        bnC[c] = fmaf(-a, mean, be[c]);
    }
}

// ---------------------------------------------------------------- final agg + log_softmax
__global__ __launch_bounds__(256) void k_agg32_lsm(const float* __restrict__ Z,
                                                   float* __restrict__ Out,
                                                   const float* __restrict__ bias,
                                                   const int* __restrict__ row_start,
                                                   const int* __restrict__ srcs,
                                                   const float* __restrict__ wts,
                                                   const float* __restrict__ dinv) {
    int tid = threadIdx.x;
    int wid = tid >> 6, lane = tid & 63;
    int c = lane & 31;
    bool act = lane < 32;
    float bc = bias[c];
    int stride = gridDim.x * 4;
    for (int n = blockIdx.x * 4 + wid; n < NN; n += stride) {
        float dn = dinv[n];
        float a = act ? dn * Z[(size_t)n * 32 + c] : 0.f;
        int e0 = row_start[n], e1 = row_start[n + 1];
        for (int e = e0; e < e1; ++e) {
            int s = srcs[e];
            float w = wts[e];
            if (act) a = fmaf(w, Z[(size_t)s * 32 + c], a);
        }
        float v = fmaf(dn, a, bc);
        float m = v;
        for (int off = 16; off; off >>= 1) m = fmaxf(m, __shfl_xor(m, off, 32));
        float ex = __expf(v - m);
        float ssum = ex;
        for (int off = 16; off; off >>= 1) ssum += __shfl_xor(ssum, off, 32);
        float res = v - m - __logf(ssum);
        if (act) Out[(size_t)n * 32 + c] = res;
    }
}

// ---------------------------------------------------------------- launch

extern "C" void kernel_launch(void* const* d_in, const int* in_sizes, int n_in,
                              void* d_out, int out_size, void* d_ws, size_t ws_size,
                              hipStream_t stream) {
    const float* x  = (const float*)d_in[0];
    const int* ei   = (const int*)d_in[1];   // [2, NE]: src then dst
    const float* W1 = (const float*)d_in[2];
    const float* b1 = (const float*)d_in[3];
    const float* W2 = (const float*)d_in[4];
    const float* b2 = (const float*)d_in[5];
    const float* W3 = (const float*)d_in[6];
    const float* b3 = (const float*)d_in[7];
    const float* g1 = (const float*)d_in[8];
    const float* be1 = (const float*)d_in[9];
    const float* g2 = (const float*)d_in[10];
    const float* be2 = (const float*)d_in[11];
    float* out = (float*)d_out;

    const int* src = ei;
    const int* dst = ei + NE;

    char* p = (char*)d_ws;
    size_t off = 0;
    auto take = [&](size_t bytes) {
        char* r = p + off;
        off = (off + bytes + 255) & ~(size_t)255;
        return r;
    };
    float* dinv      = (float*)take(NN * 4);
    int*   deg       = (int*)take(NN * 4);
    int*   row_start = (int*)take((NN + 1) * 4);
    int*   cursor    = (int*)take(NN * 4);
    int*   ssrc      = (int*)take(NE * 4);
    float* swt       = (float*)take(NE * 4);
    float* meta      = (float*)take(768 * 4);
    float* bufA      = (float*)take((size_t)NN * HID * 4);
    float* bufB      = (float*)take((size_t)NN * HID * 4);

    float* sum1 = meta + 0,   *sq1 = meta + 96;
    float* sum2 = meta + 192, *sq2 = meta + 288;
    float* bnA1 = meta + 384, *bnC1 = meta + 480;
    float* bnA2 = meta + 576, *bnC2 = meta + 672;

    hipMemsetAsync(deg, 0, NN * 4, stream);
    hipMemsetAsync(cursor, 0, NN * 4, stream);
    hipMemsetAsync(meta, 0, 384 * 4, stream);  // sums/sumsqs

    const int EB = (NE + 255) / 256;
    const int VB = (NN + 255) / 256;
    k_hist<<<EB, 256, 0, stream>>>(dst, deg);
    k_dinv<<<VB, 256, 0, stream>>>(deg, dinv);
    k_scan<<<1, 1024, 0, stream>>>(deg, row_start);
    k_scatter<<<EB, 256, 0, stream>>>(src, dst, row_start, cursor, dinv, ssrc, swt);

    const int GB = (NN + 63) / 64;  // 1563 GEMM blocks
    const int AB = 2560;            // agg blocks (grid-stride, 4 waves each)

    // layer 1: z = x@W1 ; h1 = agg(z)+b1 (+stats)
    k_gemm<DIN, HID, false><<<GB, 256, 0, stream>>>(x, W1, bufA, nullptr, nullptr, NN);
    k_agg96<<<AB, 256, 0, stream>>>(bufA, bufB, b1, row_start, ssrc, swt, dinv, sum1, sq1);
    k_bncoef<<<1, 128, 0, stream>>>(sum1, sq1, g1, be1, bnA1, bnC1);

    // layer 2: z = relu(bn(h1))@W2 ; h2 = agg(z)+b2 (+stats)
    k_gemm<HID, HID, true><<<GB, 256, 0, stream>>>(bufB, W2, bufA, bnA1, bnC1, NN);
    k_agg96<<<AB, 256, 0, stream>>>(bufA, bufB, b2, row_start, ssrc, swt, dinv, sum2, sq2);
    k_bncoef<<<1, 128, 0, stream>>>(sum2, sq2, g2, be2, bnA2, bnC2);

    // layer 3: z = relu(bn(h2))@W3 ; out = log_softmax(agg(z)+b3)
    k_gemm<HID, DOUT, true><<<GB, 256, 0, stream>>>(bufB, W3, bufA, bnA2, bnC2, NN);
    k_agg32_lsm<<<AB, 256, 0, stream>>>(bufA, out, b3, row_start, ssrc, swt, dinv);

    (void)in_sizes; (void)n_in; (void)out_size; (void)ws_size;
}

// Round 2
// 774.526 us; speedup vs baseline: 1.2054x; 1.2054x over previous
//
#include <hip/hip_runtime.h>
#include <cstddef>

#define NN 100000
#define NE 800000
#define DIN 128
#define HID 96
#define DOUT 32
static constexpr float BN_EPS = 1e-5f;
#define SCAN_NB ((NN + 255) / 256)   // 391

// ---------------------------------------------------------------- setup kernels

__global__ void k_hist(const int* __restrict__ dst, int* __restrict__ deg) {
    int e = blockIdx.x * blockDim.x + threadIdx.x;
    if (e < NE) atomicAdd(&deg[dst[e]], 1);
}

__global__ void k_dinv(const int* __restrict__ deg, float* __restrict__ dinv) {
    int i = blockIdx.x * blockDim.x + threadIdx.x;
    if (i < NN) dinv[i] = rsqrtf((float)(deg[i] + 1));  // +1 self-loop, always > 0
}

// ---- 3-phase device-wide exclusive scan of deg -> row_start ----
// phase 1: per-block exclusive partials + block sums
__global__ __launch_bounds__(256) void k_scan1(const int* __restrict__ deg,
                                               int* __restrict__ row_start,
                                               int* __restrict__ blksum) {
    __shared__ int lds[256];
    int t = threadIdx.x;
    int i = blockIdx.x * 256 + t;
    int v = (i < NN) ? deg[i] : 0;
    lds[t] = v;
    __syncthreads();
#pragma unroll
    for (int off = 1; off < 256; off <<= 1) {
        int add = (t >= off) ? lds[t - off] : 0;
        __syncthreads();
        lds[t] += add;
        __syncthreads();
    }
    if (i < NN) row_start[i] = lds[t] - v;  // exclusive
    if (t == 255) blksum[blockIdx.x] = lds[255];
}

// phase 2: single block scans the 391 block sums -> exclusive offsets + grand total
__global__ __launch_bounds__(512) void k_scan2(int* __restrict__ blksum,
                                               int* __restrict__ row_start) {
    __shared__ int lds[512];
    int t = threadIdx.x;
    int v = (t < SCAN_NB) ? blksum[t] : 0;
    lds[t] = v;
    __syncthreads();
#pragma unroll
    for (int off = 1; off < 512; off <<= 1) {
        int add = (t >= off) ? lds[t - off] : 0;
        __syncthreads();
        lds[t] += add;
        __syncthreads();
    }
    if (t < SCAN_NB) blksum[t] = lds[t] - v;  // exclusive block offset
    if (t == 511) row_start[NN] = lds[SCAN_NB - 1 + (512 - SCAN_NB) * 0 + 0 + (SCAN_NB - 1) - (SCAN_NB - 1)] * 0 + lds[511];
}

// phase 3: add block offsets in place
__global__ __launch_bounds__(256) void k_scan3(int* __restrict__ row_start,
                                               const int* __restrict__ blksum) {
    int i = blockIdx.x * 256 + threadIdx.x;
    if (i < NN) row_start[i] += blksum[blockIdx.x];
}

__global__ void k_scatter(const int* __restrict__ src, const int* __restrict__ dst,
                          const int* __restrict__ row_start, int* __restrict__ cursor,
                          const float* __restrict__ dinv,
                          int* __restrict__ ssrc, float* __restrict__ swt) {
    int e = blockIdx.x * blockDim.x + threadIdx.x;
    if (e < NE) {
        int d = dst[e];
        int p = row_start[d] + atomicAdd(&cursor[d], 1);
        int s = src[e];
        ssrc[p] = s;
        swt[p] = dinv[s];
    }
}

// ---------------------------------------------------------------- GEMM (fp32 vector)
// Z[M x ND] = f(X)[M x KD] @ W[KD x ND], f = optional per-K-channel relu(a*x+c)
template <int KD, int ND, bool FUSE>
__global__ __launch_bounds__(256) void k_gemm(const float* __restrict__ X,
                                              const float* __restrict__ W,
                                              float* __restrict__ Z,
                                              const float* __restrict__ bnA,
                                              const float* __restrict__ bnC, int M) {
    constexpr int BK = 32;
    constexpr int CT = 16;
    constexpr int CPT = ND / CT;   // 6 (ND=96) or 2 (ND=32)
    constexpr int RPT = 4;         // 16 row-threads * 4 = 64 rows
    __shared__ float Xs[64 * 33];  // +1 pad: row stride 33 breaks bank aliasing
    __shared__ float Ws[BK * ND];
    __shared__ float As[KD], Cs[KD];

    int tid = threadIdx.x;
    if (FUSE && tid < KD) { As[tid] = bnA[tid]; Cs[tid] = bnC[tid]; }
    int row0 = blockIdx.x * 64;
    int ct = tid % CT, rt = tid / CT;
    float acc[RPT][CPT];
#pragma unroll
    for (int r = 0; r < RPT; ++r)
#pragma unroll
        for (int c = 0; c < CPT; ++c) acc[r][c] = 0.f;

    for (int k0 = 0; k0 < KD; k0 += BK) {
        __syncthreads();
#pragma unroll
        for (int pass = 0; pass < 2; ++pass) {
            int r = pass * 32 + (tid >> 3);
            int kq = (tid & 7) * 4;
            int grow = row0 + r;
            float4 v = make_float4(0.f, 0.f, 0.f, 0.f);
            if (grow < M) v = *(const float4*)&X[(size_t)grow * KD + k0 + kq];
            if (FUSE) {
                v.x = fmaxf(fmaf(As[k0 + kq + 0], v.x, Cs[k0 + kq + 0]), 0.f);
                v.y = fmaxf(fmaf(As[k0 + kq + 1], v.y, Cs[k0 + kq + 1]), 0.f);
                v.z = fmaxf(fmaf(As[k0 + kq + 2], v.z, Cs[k0 + kq + 2]), 0.f);
                v.w = fmaxf(fmaf(As[k0 + kq + 3], v.w, Cs[k0 + kq + 3]), 0.f);
            }
            Xs[r * 33 + kq + 0] = v.x;
            Xs[r * 33 + kq + 1] = v.y;
            Xs[r * 33 + kq + 2] = v.z;
            Xs[r * 33 + kq + 3] = v.w;
        }
#pragma unroll
        for (int f = tid; f < BK * ND / 4; f += 256) {
            int kk = f / (ND / 4);
            int c4 = (f % (ND / 4)) * 4;
            *(float4*)&Ws[kk * ND + c4] = *(const float4*)&W[(size_t)(k0 + kk) * ND + c4];
        }
        __syncthreads();
#pragma unroll
        for (int kk = 0; kk < BK; ++kk) {
            float xr[RPT];
#pragma unroll
            for (int r = 0; r < RPT; ++r) xr[r] = Xs[(rt * RPT + r) * 33 + kk];
            float wc[CPT];
#pragma unroll
            for (int c = 0; c < CPT; ++c) wc[c] = Ws[kk * ND + ct * CPT + c];
#pragma unroll
            for (int r = 0; r < RPT; ++r)
#pragma unroll
                for (int c = 0; c < CPT; ++c) acc[r][c] = fmaf(xr[r], wc[c], acc[r][c]);
        }
    }
#pragma unroll
    for (int r = 0; r < RPT; ++r) {
        int grow = row0 + rt * RPT + r;
        if (grow < M) {
#pragma unroll
            for (int c = 0; c < CPT; ++c)
                Z[(size_t)grow * ND + ct * CPT + c] = acc[r][c];
        }
    }
}

// ---------------------------------------------------------------- aggregation, 96ch
__global__ __launch_bounds__(256) void k_agg96(const float* __restrict__ Z,
                                               float* __restrict__ H,
                                               const float* __restrict__ bias,
                                               const int* __restrict__ row_start,
                                               const int* __restrict__ srcs,
                                               const float* __restrict__ wts,
                                               const float* __restrict__ dinv,
                                               float* __restrict__ gsum,
                                               float* __restrict__ gsq) {
    __shared__ float ssum[96], ssq[96];
    int tid = threadIdx.x;
    if (tid < 96) { ssum[tid] = 0.f; ssq[tid] = 0.f; }
    __syncthreads();
    int wid = tid >> 6, lane = tid & 63;
    int c0 = lane, c1 = 64 + lane;
    bool has1 = lane < 32;
    float b0 = bias[c0], b1v = has1 ? bias[c1] : 0.f;
    float lsum0 = 0.f, lsq0 = 0.f, lsum1 = 0.f, lsq1 = 0.f;
    int stride = gridDim.x * 4;
    for (int n = blockIdx.x * 4 + wid; n < NN; n += stride) {
        float dn = dinv[n];
        const float* zn = Z + (size_t)n * 96;
        float a0 = dn * zn[c0];
        float a1 = has1 ? dn * zn[c1] : 0.f;
        int e0 = row_start[n], e1 = row_start[n + 1];
        for (int e = e0; e < e1; ++e) {
            int s = srcs[e];
            float w = wts[e];
            const float* zs = Z + (size_t)s * 96;
            a0 = fmaf(w, zs[c0], a0);
            if (has1) a1 = fmaf(w, zs[c1], a1);
        }
        float h0 = fmaf(dn, a0, b0);
        H[(size_t)n * 96 + c0] = h0;
        lsum0 += h0; lsq0 = fmaf(h0, h0, lsq0);
        if (has1) {
            float h1 = fmaf(dn, a1, b1v);
            H[(size_t)n * 96 + c1] = h1;
            lsum1 += h1; lsq1 = fmaf(h1, h1, lsq1);
        }
    }
    atomicAdd(&ssum[c0], lsum0); atomicAdd(&ssq[c0], lsq0);
    if (has1) { atomicAdd(&ssum[c1], lsum1); atomicAdd(&ssq[c1], lsq1); }
    __syncthreads();
    if (tid < 96) { atomicAdd(&gsum[tid], ssum[tid]); atomicAdd(&gsq[tid], ssq[tid]); }
}

__global__ void k_bncoef(const float* __restrict__ gsum, const float* __restrict__ gsq,
                         const float* __restrict__ g, const float* __restrict__ be,
                         float* __restrict__ bnA, float* __restrict__ bnC) {
    int c = threadIdx.x;
    if (c < 96) {
        float mean = gsum[c] * (1.f / NN);
        float var = gsq[c] * (1.f / NN) - mean * mean;
        float inv = rsqrtf(var + BN_EPS);
        float a = g[c] * inv;
        bnA[c] = a;
        bnC[c] = fmaf(-a, mean, be[c]);
    }
}

// ---------------------------------------------------------------- final agg + log_softmax
__global__ __launch_bounds__(256) void k_agg32_lsm(const float* __restrict__ Z,
                                                   float* __restrict__ Out,
                                                   const float* __restrict__ bias,
                                                   const int* __restrict__ row_start,
                                                   const int* __restrict__ srcs,
                                                   const float* __restrict__ wts,
                                                   const float* __restrict__ dinv) {
    int tid = threadIdx.x;
    int wid = tid >> 6, lane = tid & 63;
    int c = lane & 31;
    bool act = lane < 32;
    float bc = bias[c];
    int stride = gridDim.x * 4;
    for (int n = blockIdx.x * 4 + wid; n < NN; n += stride) {
        float dn = dinv[n];
        float a = act ? dn * Z[(size_t)n * 32 + c] : 0.f;
        int e0 = row_start[n], e1 = row_start[n + 1];
        for (int e = e0; e < e1; ++e) {
            int s = srcs[e];
            float w = wts[e];
            if (act) a = fmaf(w, Z[(size_t)s * 32 + c], a);
        }
        float v = fmaf(dn, a, bc);
        float m = v;
        for (int off = 16; off; off >>= 1) m = fmaxf(m, __shfl_xor(m, off, 32));
        float ex = __expf(v - m);
        float ssum = ex;
        for (int off = 16; off; off >>= 1) ssum += __shfl_xor(ssum, off, 32);
        float res = v - m - __logf(ssum);
        if (act) Out[(size_t)n * 32 + c] = res;
    }
}

// ---------------------------------------------------------------- launch

extern "C" void kernel_launch(void* const* d_in, const int* in_sizes, int n_in,
                              void* d_out, int out_size, void* d_ws, size_t ws_size,
                              hipStream_t stream) {
    const float* x  = (const float*)d_in[0];
    const int* ei   = (const int*)d_in[1];   // [2, NE]: src then dst
    const float* W1 = (const float*)d_in[2];
    const float* b1 = (const float*)d_in[3];
    const float* W2 = (const float*)d_in[4];
    const float* b2 = (const float*)d_in[5];
    const float* W3 = (const float*)d_in[6];
    const float* b3 = (const float*)d_in[7];
    const float* g1 = (const float*)d_in[8];
    const float* be1 = (const float*)d_in[9];
    const float* g2 = (const float*)d_in[10];
    const float* be2 = (const float*)d_in[11];
    float* out = (float*)d_out;

    const int* src = ei;
    const int* dst = ei + NE;

    char* p = (char*)d_ws;
    size_t off = 0;
    auto take = [&](size_t bytes) {
        char* r = p + off;
        off = (off + bytes + 255) & ~(size_t)255;
        return r;
    };
    float* dinv      = (float*)take(NN * 4);
    int*   deg       = (int*)take(NN * 4);
    int*   row_start = (int*)take((NN + 1) * 4);
    int*   cursor    = (int*)take(NN * 4);
    int*   blksum    = (int*)take(SCAN_NB * 4);
    int*   ssrc      = (int*)take(NE * 4);
    float* swt       = (float*)take(NE * 4);
    float* meta      = (float*)take(768 * 4);
    float* bufA      = (float*)take((size_t)NN * HID * 4);
    float* bufB      = (float*)take((size_t)NN * HID * 4);

    float* sum1 = meta + 0,   *sq1 = meta + 96;
    float* sum2 = meta + 192, *sq2 = meta + 288;
    float* bnA1 = meta + 384, *bnC1 = meta + 480;
    float* bnA2 = meta + 576, *bnC2 = meta + 672;

    hipMemsetAsync(deg, 0, NN * 4, stream);
    hipMemsetAsync(cursor, 0, NN * 4, stream);
    hipMemsetAsync(meta, 0, 384 * 4, stream);  // sums/sumsqs

    const int EB = (NE + 255) / 256;
    const int VB = (NN + 255) / 256;
    k_hist<<<EB, 256, 0, stream>>>(dst, deg);
    k_dinv<<<VB, 256, 0, stream>>>(deg, dinv);
    k_scan1<<<SCAN_NB, 256, 0, stream>>>(deg, row_start, blksum);
    k_scan2<<<1, 512, 0, stream>>>(blksum, row_start);
    k_scan3<<<SCAN_NB, 256, 0, stream>>>(row_start, blksum);
    k_scatter<<<EB, 256, 0, stream>>>(src, dst, row_start, cursor, dinv, ssrc, swt);

    const int GB = (NN + 63) / 64;  // 1563 GEMM blocks
    const int AB = 2560;            // agg blocks (grid-stride, 4 waves each)

    // layer 1: z = x@W1 ; h1 = agg(z)+b1 (+stats)
    k_gemm<DIN, HID, false><<<GB, 256, 0, stream>>>(x, W1, bufA, nullptr, nullptr, NN);
    k_agg96<<<AB, 256, 0, stream>>>(bufA, bufB, b1, row_start, ssrc, swt, dinv, sum1, sq1);
    k_bncoef<<<1, 128, 0, stream>>>(sum1, sq1, g1, be1, bnA1, bnC1);

    // layer 2: z = relu(bn(h1))@W2 ; h2 = agg(z)+b2 (+stats)
    k_gemm<HID, HID, true><<<GB, 256, 0, stream>>>(bufB, W2, bufA, bnA1, bnC1, NN);
    k_agg96<<<AB, 256, 0, stream>>>(bufA, bufB, b2, row_start, ssrc, swt, dinv, sum2, sq2);
    k_bncoef<<<1, 128, 0, stream>>>(sum2, sq2, g2, be2, bnA2, bnC2);

    // layer 3: z = relu(bn(h2))@W3 ; out = log_softmax(agg(z)+b3)
    k_gemm<HID, DOUT, true><<<GB, 256, 0, stream>>>(bufB, W3, bufA, bnA2, bnC2, NN);
    k_agg32_lsm<<<AB, 256, 0, stream>>>(bufA, out, b3, row_start, ssrc, swt, dinv);

    (void)in_sizes; (void)n_in; (void)out_size; (void)ws_size;
}

// Round 3
// 579.101 us; speedup vs baseline: 1.6122x; 1.3375x over previous
//
#include <hip/hip_runtime.h>
#include <cstddef>

#define NN 100000
#define NE 800000
#define DIN 128
#define HID 96
#define DOUT 32
static constexpr float BN_EPS = 1e-5f;
#define SCAN_NB ((NN + 255) / 256)   // 391

typedef unsigned short u16;
typedef unsigned int u32;

__device__ __forceinline__ float b2f(u32 lo16) {
    union { u32 u; float f; } c; c.u = lo16 << 16; return c.f;
}
__device__ __forceinline__ u16 f2b(float f) {
    union { float f; u32 u; } c; c.f = f;
    return (u16)((c.u + 0x7FFFu + ((c.u >> 16) & 1u)) >> 16);
}

// ---------------------------------------------------------------- setup kernels

__global__ void k_hist(const int* __restrict__ dst, int* __restrict__ deg) {
    int e = blockIdx.x * blockDim.x + threadIdx.x;
    if (e < NE) atomicAdd(&deg[dst[e]], 1);
}

__global__ void k_dinv(const int* __restrict__ deg, float* __restrict__ dinv) {
    int i = blockIdx.x * blockDim.x + threadIdx.x;
    if (i < NN) dinv[i] = rsqrtf((float)(deg[i] + 1));  // +1 self-loop, always > 0
}

__global__ __launch_bounds__(256) void k_scan1(const int* __restrict__ deg,
                                               int* __restrict__ row_start,
                                               int* __restrict__ blksum) {
    __shared__ int lds[256];
    int t = threadIdx.x;
    int i = blockIdx.x * 256 + t;
    int v = (i < NN) ? deg[i] : 0;
    lds[t] = v;
    __syncthreads();
#pragma unroll
    for (int off = 1; off < 256; off <<= 1) {
        int add = (t >= off) ? lds[t - off] : 0;
        __syncthreads();
        lds[t] += add;
        __syncthreads();
    }
    if (i < NN) row_start[i] = lds[t] - v;  // exclusive
    if (t == 255) blksum[blockIdx.x] = lds[255];
}

__global__ __launch_bounds__(512) void k_scan2(int* __restrict__ blksum,
                                               int* __restrict__ row_start) {
    __shared__ int lds[512];
    int t = threadIdx.x;
    int v = (t < SCAN_NB) ? blksum[t] : 0;
    lds[t] = v;
    __syncthreads();
#pragma unroll
    for (int off = 1; off < 512; off <<= 1) {
        int add = (t >= off) ? lds[t - off] : 0;
        __syncthreads();
        lds[t] += add;
        __syncthreads();
    }
    if (t < SCAN_NB) blksum[t] = lds[t] - v;  // exclusive block offset
    if (t == 511) row_start[NN] = lds[511];   // grand total (= NE)
}

__global__ __launch_bounds__(256) void k_scan3(int* __restrict__ row_start,
                                               const int* __restrict__ blksum) {
    int i = blockIdx.x * 256 + threadIdx.x;
    if (i < NN) row_start[i] += blksum[blockIdx.x];
}

__global__ void k_scatter(const int* __restrict__ src, const int* __restrict__ dst,
                          const int* __restrict__ row_start, int* __restrict__ cursor,
                          const float* __restrict__ dinv,
                          int2* __restrict__ ewt) {
    int e = blockIdx.x * blockDim.x + threadIdx.x;
    if (e < NE) {
        int d = dst[e];
        int p = row_start[d] + atomicAdd(&cursor[d], 1);
        int s = src[e];
        ewt[p] = make_int2(s, __float_as_int(dinv[s]));
    }
}

// ---------------------------------------------------------------- GEMM (fp32 vector)
// Z[M x ND](bf16) = f(X)[M x KD] @ W[KD x ND], f = optional relu(a*x+c) per K-channel
// XT = float (layer 1) or u16/bf16 (layers 2,3).
template <int KD, int ND, bool FUSE, typename XT>
__global__ __launch_bounds__(256) void k_gemm(const XT* __restrict__ X,
                                              const float* __restrict__ W,
                                              u16* __restrict__ Z,
                                              const float* __restrict__ bnA,
                                              const float* __restrict__ bnC, int M) {
    constexpr int BK = 32;
    constexpr int CT = 16;
    constexpr int CPT = ND / CT;   // 6 (ND=96) or 2 (ND=32)
    constexpr int RPT = 4;         // 16 row-threads * 4 = 64 rows
    __shared__ float Xs[64 * 33];  // +1 pad breaks bank aliasing
    __shared__ float Ws[BK * ND];
    __shared__ float As[KD], Cs[KD];

    int tid = threadIdx.x;
    if (FUSE && tid < KD) { As[tid] = bnA[tid]; Cs[tid] = bnC[tid]; }
    int row0 = blockIdx.x * 64;
    int ct = tid % CT, rt = tid / CT;
    float acc[RPT][CPT];
#pragma unroll
    for (int r = 0; r < RPT; ++r)
#pragma unroll
        for (int c = 0; c < CPT; ++c) acc[r][c] = 0.f;

    for (int k0 = 0; k0 < KD; k0 += BK) {
        __syncthreads();
        if constexpr (sizeof(XT) == 4) {
            // fp32 X: float4/thread, 2 passes of 32 rows
#pragma unroll
            for (int pass = 0; pass < 2; ++pass) {
                int r = pass * 32 + (tid >> 3);
                int kq = (tid & 7) * 4;
                int grow = row0 + r;
                float4 v = make_float4(0.f, 0.f, 0.f, 0.f);
                if (grow < M) v = *(const float4*)&X[(size_t)grow * KD + k0 + kq];
                if (FUSE) {
                    v.x = fmaxf(fmaf(As[k0 + kq + 0], v.x, Cs[k0 + kq + 0]), 0.f);
                    v.y = fmaxf(fmaf(As[k0 + kq + 1], v.y, Cs[k0 + kq + 1]), 0.f);
                    v.z = fmaxf(fmaf(As[k0 + kq + 2], v.z, Cs[k0 + kq + 2]), 0.f);
                    v.w = fmaxf(fmaf(As[k0 + kq + 3], v.w, Cs[k0 + kq + 3]), 0.f);
                }
                Xs[r * 33 + kq + 0] = v.x;
                Xs[r * 33 + kq + 1] = v.y;
                Xs[r * 33 + kq + 2] = v.z;
                Xs[r * 33 + kq + 3] = v.w;
            }
        } else {
            // bf16 X: 16B = 8 elems/thread, 4 threads/row, one pass of 64 rows
            int r = tid >> 2;
            int kq = (tid & 3) * 8;
            int grow = row0 + r;
            uint4 v = make_uint4(0, 0, 0, 0);
            if (grow < M) v = *(const uint4*)&X[(size_t)grow * KD + k0 + kq];
            u32 w[4] = {v.x, v.y, v.z, v.w};
#pragma unroll
            for (int q = 0; q < 4; ++q) {
                float lo = b2f(w[q] & 0xFFFFu);
                float hi = b2f(w[q] >> 16);
                if (FUSE) {
                    lo = fmaxf(fmaf(As[k0 + kq + 2 * q + 0], lo, Cs[k0 + kq + 2 * q + 0]), 0.f);
                    hi = fmaxf(fmaf(As[k0 + kq + 2 * q + 1], hi, Cs[k0 + kq + 2 * q + 1]), 0.f);
                }
                Xs[r * 33 + kq + 2 * q + 0] = lo;
                Xs[r * 33 + kq + 2 * q + 1] = hi;
            }
        }
#pragma unroll
        for (int f = tid; f < BK * ND / 4; f += 256) {
            int kk = f / (ND / 4);
            int c4 = (f % (ND / 4)) * 4;
            *(float4*)&Ws[kk * ND + c4] = *(const float4*)&W[(size_t)(k0 + kk) * ND + c4];
        }
        __syncthreads();
#pragma unroll
        for (int kk = 0; kk < BK; ++kk) {
            float xr[RPT];
#pragma unroll
            for (int r = 0; r < RPT; ++r) xr[r] = Xs[(rt * RPT + r) * 33 + kk];
            float wc[CPT];
#pragma unroll
            for (int c = 0; c < CPT; ++c) wc[c] = Ws[kk * ND + ct * CPT + c];
#pragma unroll
            for (int r = 0; r < RPT; ++r)
#pragma unroll
                for (int c = 0; c < CPT; ++c) acc[r][c] = fmaf(xr[r], wc[c], acc[r][c]);
        }
    }
#pragma unroll
    for (int r = 0; r < RPT; ++r) {
        int grow = row0 + rt * RPT + r;
        if (grow < M) {
#pragma unroll
            for (int c = 0; c < CPT; c += 2) {
                u32 pk = (u32)f2b(acc[r][c]) | ((u32)f2b(acc[r][c + 1]) << 16);
                *(u32*)&Z[(size_t)grow * ND + ct * CPT + c] = pk;
            }
        }
    }
}

// ---------------------------------------------------------------- aggregation, 96ch (bf16)
// one wave per node; lane l<48 holds channel pair (2l, 2l+1) as one dword gather.
// edge (src,wt) pairs preloaded 64-wide, broadcast via shfl. Fuses +bias + BN stats.
__global__ __launch_bounds__(256) void k_agg96(const u16* __restrict__ Z,
                                               u16* __restrict__ H,
                                               const float* __restrict__ bias,
                                               const int* __restrict__ row_start,
                                               const int2* __restrict__ ewt,
                                               const float* __restrict__ dinv,
                                               float* __restrict__ gsum,
                                               float* __restrict__ gsq) {
    __shared__ float ssum[96], ssq[96];
    int tid = threadIdx.x;
    if (tid < 96) { ssum[tid] = 0.f; ssq[tid] = 0.f; }
    __syncthreads();
    int wid = tid >> 6, lane = tid & 63;
    bool act = lane < 48;
    int l = act ? lane : 47;
    const u32* zu = (const u32*)Z;          // row stride 48 dwords
    float b0 = bias[2 * l], b1 = bias[2 * l + 1];
    float lsum0 = 0.f, lsq0 = 0.f, lsum1 = 0.f, lsq1 = 0.f;
    int stride = gridDim.x * 4;
    for (int n = blockIdx.x * 4 + wid; n < NN; n += stride) {
        float dn = dinv[n];
        u32 uself = zu[(size_t)n * 48 + l];
        float a0 = dn * b2f(uself & 0xFFFFu);
        float a1 = dn * b2f(uself >> 16);
        int e0 = row_start[n], e1 = row_start[n + 1];
        for (int eb = e0; eb < e1; eb += 64) {
            int m = e1 - eb; if (m > 64) m = 64;
            int idx = eb + lane;
            int2 pr = (idx < e1) ? ewt[idx] : make_int2(0, 0);
            int sl = pr.x; float wl = __int_as_float(pr.y);
            int j = 0;
            for (; j + 4 <= m; j += 4) {
                int s0 = __shfl(sl, j), s1 = __shfl(sl, j + 1);
                int s2 = __shfl(sl, j + 2), s3 = __shfl(sl, j + 3);
                float w0 = __shfl(wl, j), w1 = __shfl(wl, j + 1);
                float w2 = __shfl(wl, j + 2), w3 = __shfl(wl, j + 3);
                u32 u0 = zu[(size_t)s0 * 48 + l];
                u32 u1 = zu[(size_t)s1 * 48 + l];
                u32 u2 = zu[(size_t)s2 * 48 + l];
                u32 u3 = zu[(size_t)s3 * 48 + l];
                a0 = fmaf(w0, b2f(u0 & 0xFFFFu), a0); a1 = fmaf(w0, b2f(u0 >> 16), a1);
                a0 = fmaf(w1, b2f(u1 & 0xFFFFu), a0); a1 = fmaf(w1, b2f(u1 >> 16), a1);
                a0 = fmaf(w2, b2f(u2 & 0xFFFFu), a0); a1 = fmaf(w2, b2f(u2 >> 16), a1);
                a0 = fmaf(w3, b2f(u3 & 0xFFFFu), a0); a1 = fmaf(w3, b2f(u3 >> 16), a1);
            }
            for (; j < m; ++j) {
                int s = __shfl(sl, j);
                float w = __shfl(wl, j);
                u32 u = zu[(size_t)s * 48 + l];
                a0 = fmaf(w, b2f(u & 0xFFFFu), a0);
                a1 = fmaf(w, b2f(u >> 16), a1);
            }
        }
        float h0 = fmaf(dn, a0, b0);
        float h1 = fmaf(dn, a1, b1);
        if (act) {
            u32 pk = (u32)f2b(h0) | ((u32)f2b(h1) << 16);
            ((u32*)H)[(size_t)n * 48 + l] = pk;
            lsum0 += h0; lsq0 = fmaf(h0, h0, lsq0);
            lsum1 += h1; lsq1 = fmaf(h1, h1, lsq1);
        }
    }
    if (act) {
        atomicAdd(&ssum[2 * l], lsum0); atomicAdd(&ssq[2 * l], lsq0);
        atomicAdd(&ssum[2 * l + 1], lsum1); atomicAdd(&ssq[2 * l + 1], lsq1);
    }
    __syncthreads();
    if (tid < 96) { atomicAdd(&gsum[tid], ssum[tid]); atomicAdd(&gsq[tid], ssq[tid]); }
}

__global__ void k_bncoef(const float* __restrict__ gsum, const float* __restrict__ gsq,
                         const float* __restrict__ g, const float* __restrict__ be,
                         float* __restrict__ bnA, float* __restrict__ bnC) {
    int c = threadIdx.x;
    if (c < 96) {
        float mean = gsum[c] * (1.f / NN);
        float var = gsq[c] * (1.f / NN) - mean * mean;
        float inv = rsqrtf(var + BN_EPS);
        float a = g[c] * inv;
        bnA[c] = a;
        bnC[c] = fmaf(-a, mean, be[c]);
    }
}

// ---------------------------------------------------------------- final agg + log_softmax
// 4 nodes per wave; 16-lane group per node; lane pair-channels (2sl, 2sl+1).
__global__ __launch_bounds__(256) void k_agg32_lsm(const u16* __restrict__ Z,
                                                   float* __restrict__ Out,
                                                   const float* __restrict__ bias,
                                                   const int* __restrict__ row_start,
                                                   const int2* __restrict__ ewt,
                                                   const float* __restrict__ dinv) {
    int tid = threadIdx.x;
    int wid = tid >> 6, lane = tid & 63;
    int g = lane >> 4, sl = lane & 15;
    const u32* zu = (const u32*)Z;  // row stride 16 dwords
    float b0 = bias[2 * sl], b1 = bias[2 * sl + 1];
    int stride = gridDim.x * 16;
    for (int n0 = (blockIdx.x * 4 + wid) * 4; n0 < NN; n0 += stride) {
        int n = n0 + g;
        bool vn = n < NN;
        float dn = vn ? dinv[n] : 0.f;
        u32 uself = vn ? zu[(size_t)n * 16 + sl] : 0;
        float a0 = dn * b2f(uself & 0xFFFFu);
        float a1 = dn * b2f(uself >> 16);
        int e0 = vn ? row_start[n] : 0, e1 = vn ? row_start[n + 1] : 0;
        for (int eb = e0; eb < e1; eb += 16) {
            int m = e1 - eb; if (m > 16) m = 16;
            int idx = eb + sl;
            int2 pr = (idx < e1) ? ewt[idx] : make_int2(0, 0);
            int slv = pr.x; float wlv = __int_as_float(pr.y);
            int j = 0;
            for (; j + 4 <= m; j += 4) {
                int s0 = __shfl(slv, j, 16), s1 = __shfl(slv, j + 1, 16);
                int s2 = __shfl(slv, j + 2, 16), s3 = __shfl(slv, j + 3, 16);
                float w0 = __shfl(wlv, j, 16), w1 = __shfl(wlv, j + 1, 16);
                float w2 = __shfl(wlv, j + 2, 16), w3 = __shfl(wlv, j + 3, 16);
                u32 u0 = zu[(size_t)s0 * 16 + sl];
                u32 u1 = zu[(size_t)s1 * 16 + sl];
                u32 u2 = zu[(size_t)s2 * 16 + sl];
                u32 u3 = zu[(size_t)s3 * 16 + sl];
                a0 = fmaf(w0, b2f(u0 & 0xFFFFu), a0); a1 = fmaf(w0, b2f(u0 >> 16), a1);
                a0 = fmaf(w1, b2f(u1 & 0xFFFFu), a0); a1 = fmaf(w1, b2f(u1 >> 16), a1);
                a0 = fmaf(w2, b2f(u2 & 0xFFFFu), a0); a1 = fmaf(w2, b2f(u2 >> 16), a1);
                a0 = fmaf(w3, b2f(u3 & 0xFFFFu), a0); a1 = fmaf(w3, b2f(u3 >> 16), a1);
            }
            for (; j < m; ++j) {
                int s = __shfl(slv, j, 16);
                float w = __shfl(wlv, j, 16);
                u32 u = zu[(size_t)s * 16 + sl];
                a0 = fmaf(w, b2f(u & 0xFFFFu), a0);
                a1 = fmaf(w, b2f(u >> 16), a1);
            }
        }
        float v0 = fmaf(dn, a0, b0);
        float v1 = fmaf(dn, a1, b1);
        float mx = fmaxf(v0, v1);
#pragma unroll
        for (int off = 8; off; off >>= 1) mx = fmaxf(mx, __shfl_xor(mx, off, 16));
        float ex = __expf(v0 - mx) + __expf(v1 - mx);
#pragma unroll
        for (int off = 8; off; off >>= 1) ex += __shfl_xor(ex, off, 16);
        float lse = mx + __logf(ex);
        if (vn) {
            float2 o = make_float2(v0 - lse, v1 - lse);
            *(float2*)&Out[(size_t)n * 32 + 2 * sl] = o;
        }
    }
}

// ---------------------------------------------------------------- launch

extern "C" void kernel_launch(void* const* d_in, const int* in_sizes, int n_in,
                              void* d_out, int out_size, void* d_ws, size_t ws_size,
                              hipStream_t stream) {
    const float* x  = (const float*)d_in[0];
    const int* ei   = (const int*)d_in[1];   // [2, NE]: src then dst
    const float* W1 = (const float*)d_in[2];
    const float* b1 = (const float*)d_in[3];
    const float* W2 = (const float*)d_in[4];
    const float* b2 = (const float*)d_in[5];
    const float* W3 = (const float*)d_in[6];
    const float* b3 = (const float*)d_in[7];
    const float* g1 = (const float*)d_in[8];
    const float* be1 = (const float*)d_in[9];
    const float* g2 = (const float*)d_in[10];
    const float* be2 = (const float*)d_in[11];
    float* out = (float*)d_out;

    const int* src = ei;
    const int* dst = ei + NE;

    char* p = (char*)d_ws;
    size_t off = 0;
    auto take = [&](size_t bytes) {
        char* r = p + off;
        off = (off + bytes + 255) & ~(size_t)255;
        return r;
    };
    float* dinv      = (float*)take(NN * 4);
    int*   deg       = (int*)take(NN * 4);
    int*   row_start = (int*)take((NN + 1) * 4);
    int*   cursor    = (int*)take(NN * 4);
    int*   blksum    = (int*)take(SCAN_NB * 4);
    int2*  ewt       = (int2*)take((size_t)NE * 8);
    float* meta      = (float*)take(768 * 4);
    u16*   bufA      = (u16*)take((size_t)NN * HID * 2);
    u16*   bufB      = (u16*)take((size_t)NN * HID * 2);

    float* sum1 = meta + 0,   *sq1 = meta + 96;
    float* sum2 = meta + 192, *sq2 = meta + 288;
    float* bnA1 = meta + 384, *bnC1 = meta + 480;
    float* bnA2 = meta + 576, *bnC2 = meta + 672;

    hipMemsetAsync(deg, 0, NN * 4, stream);
    hipMemsetAsync(cursor, 0, NN * 4, stream);
    hipMemsetAsync(meta, 0, 384 * 4, stream);  // sums/sumsqs

    const int EB = (NE + 255) / 256;
    const int VB = (NN + 255) / 256;
    k_hist<<<EB, 256, 0, stream>>>(dst, deg);
    k_dinv<<<VB, 256, 0, stream>>>(deg, dinv);
    k_scan1<<<SCAN_NB, 256, 0, stream>>>(deg, row_start, blksum);
    k_scan2<<<1, 512, 0, stream>>>(blksum, row_start);
    k_scan3<<<SCAN_NB, 256, 0, stream>>>(row_start, blksum);
    k_scatter<<<EB, 256, 0, stream>>>(src, dst, row_start, cursor, dinv, ewt);

    const int GB = (NN + 63) / 64;  // 1563 GEMM blocks
    const int AB = 2560;            // agg blocks (grid-stride)

    // layer 1: z = x@W1 ; h1 = agg(z)+b1 (+stats)
    k_gemm<DIN, HID, false, float><<<GB, 256, 0, stream>>>(x, W1, bufA, nullptr, nullptr, NN);
    k_agg96<<<AB, 256, 0, stream>>>(bufA, bufB, b1, row_start, ewt, dinv, sum1, sq1);
    k_bncoef<<<1, 128, 0, stream>>>(sum1, sq1, g1, be1, bnA1, bnC1);

    // layer 2: z = relu(bn(h1))@W2 ; h2 = agg(z)+b2 (+stats)
    k_gemm<HID, HID, true, u16><<<GB, 256, 0, stream>>>(bufB, W2, bufA, bnA1, bnC1, NN);
    k_agg96<<<AB, 256, 0, stream>>>(bufA, bufB, b2, row_start, ewt, dinv, sum2, sq2);
    k_bncoef<<<1, 128, 0, stream>>>(sum2, sq2, g2, be2, bnA2, bnC2);

    // layer 3: z = relu(bn(h2))@W3 ; out = log_softmax(agg(z)+b3)
    k_gemm<HID, DOUT, true, u16><<<GB, 256, 0, stream>>>(bufB, W3, bufA, bnA2, bnC2, NN);
    k_agg32_lsm<<<AB, 256, 0, stream>>>(bufA, out, b3, row_start, ewt, dinv);

    (void)in_sizes; (void)n_in; (void)out_size; (void)ws_size;
}

// Round 5
// 564.833 us; speedup vs baseline: 1.6529x; 1.0253x over previous
//
#include <hip/hip_runtime.h>
#include <cstddef>

#define NN 100000
#define NE 800000
#define DIN 128
#define HID 96
#define DOUT 32
static constexpr float BN_EPS = 1e-5f;
#define SCAN_NB ((NN + 255) / 256)   // 391

typedef unsigned short u16;
typedef unsigned int u32;

__device__ __forceinline__ float b2f(u32 lo16) {
    union { u32 u; float f; } c; c.u = lo16 << 16; return c.f;
}
__device__ __forceinline__ u16 f2b(float f) {
    union { float f; u32 u; } c; c.f = f;
    return (u16)((c.u + 0x7FFFu + ((c.u >> 16) & 1u)) >> 16);
}

// ---------------------------------------------------------------- setup kernels

__global__ void k_hist(const int* __restrict__ dst, int* __restrict__ deg) {
    int e = blockIdx.x * blockDim.x + threadIdx.x;
    if (e < NE) atomicAdd(&deg[dst[e]], 1);
}

__global__ void k_dinv(const int* __restrict__ deg, float* __restrict__ dinv) {
    int i = blockIdx.x * blockDim.x + threadIdx.x;
    if (i < NN) dinv[i] = rsqrtf((float)(deg[i] + 1));  // +1 self-loop, always > 0
}

__global__ __launch_bounds__(256) void k_scan1(const int* __restrict__ deg,
                                               int* __restrict__ row_start,
                                               int* __restrict__ blksum) {
    __shared__ int lds[256];
    int t = threadIdx.x;
    int i = blockIdx.x * 256 + t;
    int v = (i < NN) ? deg[i] : 0;
    lds[t] = v;
    __syncthreads();
#pragma unroll
    for (int off = 1; off < 256; off <<= 1) {
        int add = (t >= off) ? lds[t - off] : 0;
        __syncthreads();
        lds[t] += add;
        __syncthreads();
    }
    if (i < NN) row_start[i] = lds[t] - v;  // exclusive
    if (t == 255) blksum[blockIdx.x] = lds[255];
}

__global__ __launch_bounds__(512) void k_scan2(int* __restrict__ blksum,
                                               int* __restrict__ row_start) {
    __shared__ int lds[512];
    int t = threadIdx.x;
    int v = (t < SCAN_NB) ? blksum[t] : 0;
    lds[t] = v;
    __syncthreads();
#pragma unroll
    for (int off = 1; off < 512; off <<= 1) {
        int add = (t >= off) ? lds[t - off] : 0;
        __syncthreads();
        lds[t] += add;
        __syncthreads();
    }
    if (t < SCAN_NB) blksum[t] = lds[t] - v;  // exclusive block offset
    if (t == 511) row_start[NN] = lds[511];   // grand total (= NE)
}

__global__ __launch_bounds__(256) void k_scan3(int* __restrict__ row_start,
                                               const int* __restrict__ blksum) {
    int i = blockIdx.x * 256 + threadIdx.x;
    if (i < NN) row_start[i] += blksum[blockIdx.x];
}

__global__ void k_scatter(const int* __restrict__ src, const int* __restrict__ dst,
                          const int* __restrict__ row_start, int* __restrict__ cursor,
                          const float* __restrict__ dinv,
                          int2* __restrict__ ewt) {
    int e = blockIdx.x * blockDim.x + threadIdx.x;
    if (e < NE) {
        int d = dst[e];
        int p = row_start[d] + atomicAdd(&cursor[d], 1);
        int s = src[e];
        ewt[p] = make_int2(s, __float_as_int(dinv[s]));
    }
}

// ---------------------------------------------------------------- GEMM (fp32 vector)
// Z[M x ND](bf16) = f(X)[M x KD] @ W[KD x ND], f = optional relu(a*x+c) per K-channel
template <int KD, int ND, bool FUSE, typename XT>
__global__ __launch_bounds__(256) void k_gemm(const XT* __restrict__ X,
                                              const float* __restrict__ W,
                                              u16* __restrict__ Z,
                                              const float* __restrict__ bnA,
                                              const float* __restrict__ bnC, int M) {
    constexpr int BK = 32;
    constexpr int CT = 16;
    constexpr int CPT = ND / CT;   // 6 (ND=96) or 2 (ND=32)
    constexpr int RPT = 4;         // 16 row-threads * 4 = 64 rows
    __shared__ float Xs[64 * 33];
    __shared__ float Ws[BK * ND];
    __shared__ float As[KD], Cs[KD];

    int tid = threadIdx.x;
    if (FUSE && tid < KD) { As[tid] = bnA[tid]; Cs[tid] = bnC[tid]; }
    int row0 = blockIdx.x * 64;
    int ct = tid % CT, rt = tid / CT;
    float acc[RPT][CPT];
#pragma unroll
    for (int r = 0; r < RPT; ++r)
#pragma unroll
        for (int c = 0; c < CPT; ++c) acc[r][c] = 0.f;

    for (int k0 = 0; k0 < KD; k0 += BK) {
        __syncthreads();
        if constexpr (sizeof(XT) == 4) {
#pragma unroll
            for (int pass = 0; pass < 2; ++pass) {
                int r = pass * 32 + (tid >> 3);
                int kq = (tid & 7) * 4;
                int grow = row0 + r;
                float4 v = make_float4(0.f, 0.f, 0.f, 0.f);
                if (grow < M) v = *(const float4*)&X[(size_t)grow * KD + k0 + kq];
                if (FUSE) {
                    v.x = fmaxf(fmaf(As[k0 + kq + 0], v.x, Cs[k0 + kq + 0]), 0.f);
                    v.y = fmaxf(fmaf(As[k0 + kq + 1], v.y, Cs[k0 + kq + 1]), 0.f);
                    v.z = fmaxf(fmaf(As[k0 + kq + 2], v.z, Cs[k0 + kq + 2]), 0.f);
                    v.w = fmaxf(fmaf(As[k0 + kq + 3], v.w, Cs[k0 + kq + 3]), 0.f);
                }
                Xs[r * 33 + kq + 0] = v.x;
                Xs[r * 33 + kq + 1] = v.y;
                Xs[r * 33 + kq + 2] = v.z;
                Xs[r * 33 + kq + 3] = v.w;
            }
        } else {
            int r = tid >> 2;
            int kq = (tid & 3) * 8;
            int grow = row0 + r;
            uint4 v = make_uint4(0, 0, 0, 0);
            if (grow < M) v = *(const uint4*)&X[(size_t)grow * KD + k0 + kq];
            u32 w[4] = {v.x, v.y, v.z, v.w};
#pragma unroll
            for (int q = 0; q < 4; ++q) {
                float lo = b2f(w[q] & 0xFFFFu);
                float hi = b2f(w[q] >> 16);
                if (FUSE) {
                    lo = fmaxf(fmaf(As[k0 + kq + 2 * q + 0], lo, Cs[k0 + kq + 2 * q + 0]), 0.f);
                    hi = fmaxf(fmaf(As[k0 + kq + 2 * q + 1], hi, Cs[k0 + kq + 2 * q + 1]), 0.f);
                }
                Xs[r * 33 + kq + 2 * q + 0] = lo;
                Xs[r * 33 + kq + 2 * q + 1] = hi;
            }
        }
#pragma unroll
        for (int f = tid; f < BK * ND / 4; f += 256) {
            int kk = f / (ND / 4);
            int c4 = (f % (ND / 4)) * 4;
            *(float4*)&Ws[kk * ND + c4] = *(const float4*)&W[(size_t)(k0 + kk) * ND + c4];
        }
        __syncthreads();
#pragma unroll
        for (int kk = 0; kk < BK; ++kk) {
            float xr[RPT];
#pragma unroll
            for (int r = 0; r < RPT; ++r) xr[r] = Xs[(rt * RPT + r) * 33 + kk];
            float wc[CPT];
#pragma unroll
            for (int c = 0; c < CPT; ++c) wc[c] = Ws[kk * ND + ct * CPT + c];
#pragma unroll
            for (int r = 0; r < RPT; ++r)
#pragma unroll
                for (int c = 0; c < CPT; ++c) acc[r][c] = fmaf(xr[r], wc[c], acc[r][c]);
        }
    }
#pragma unroll
    for (int r = 0; r < RPT; ++r) {
        int grow = row0 + rt * RPT + r;
        if (grow < M) {
#pragma unroll
            for (int c = 0; c < CPT; c += 2) {
                u32 pk = (u32)f2b(acc[r][c]) | ((u32)f2b(acc[r][c + 1]) << 16);
                *(u32*)&Z[(size_t)grow * ND + ct * CPT + c] = pk;
            }
        }
    }
}

// ---------------------------------------------------------------- aggregation, 96ch (bf16)
// one wave per node; lane l<48 holds channel pair (2l,2l+1) as one dword gather.
// unroll-8 gathers w/ split accumulators + cross-node prefetch of row_start/ewt.
__global__ __launch_bounds__(256) void k_agg96(const u16* __restrict__ Z,
                                               u16* __restrict__ H,
                                               const float* __restrict__ bias,
                                               const int* __restrict__ row_start,
                                               const int2* __restrict__ ewt,
                                               const float* __restrict__ dinv,
                                               float* __restrict__ gsum,
                                               float* __restrict__ gsq) {
    __shared__ float ssum[96], ssq[96];
    int tid = threadIdx.x;
    if (tid < 96) { ssum[tid] = 0.f; ssq[tid] = 0.f; }
    __syncthreads();
    int wid = tid >> 6, lane = tid & 63;
    bool act = lane < 48;
    int l = act ? lane : 47;
    const u32* zu = (const u32*)Z;          // row stride 48 dwords
    float b0 = bias[2 * l], b1 = bias[2 * l + 1];
    float lsum0 = 0.f, lsq0 = 0.f, lsum1 = 0.f, lsq1 = 0.f;
    const int stride = gridDim.x * 4;

    int n = blockIdx.x * 4 + wid;
    int e0 = 0, e1 = 0;
    int2 pr = make_int2(0, 0);
    if (n < NN) {
        e0 = row_start[n]; e1 = row_start[n + 1];
        if (e0 + lane < e1) pr = ewt[e0 + lane];
    }
    while (n < NN) {
        // issue next node's row_start early (overlaps with this node's gathers)
        int n2 = n + stride;
        int e0n = 0, e1n = 0;
        if (n2 < NN) { e0n = row_start[n2]; e1n = row_start[n2 + 1]; }

        float dn = dinv[n];
        u32 uself = zu[(size_t)n * 48 + l];
        float a0a = dn * b2f(uself & 0xFFFFu);
        float a1a = dn * b2f(uself >> 16);
        float a0b = 0.f, a1b = 0.f;

        // first (usually only) batch from prefetched pr
        int sl = pr.x; float wl = __int_as_float(pr.y);

        // prefetch next node's first edge batch (depends on e0n; issue before fma work)
        int2 prn = make_int2(0, 0);
        if (n2 < NN && e0n + lane < e1n) prn = ewt[e0n + lane];

        for (int eb = e0; eb < e1; eb += 64) {
            if (eb != e0) {  // rare: deg > 64, reload batch inline
                int idx = eb + lane;
                int2 p2 = (idx < e1) ? ewt[idx] : make_int2(0, 0);
                sl = p2.x; wl = __int_as_float(p2.y);
            }
            int m = e1 - eb; if (m > 64) m = 64;
            int j = 0;
            for (; j + 8 <= m; j += 8) {
                int s_[8]; float w_[8]; u32 u_[8];
#pragma unroll
                for (int q = 0; q < 8; ++q) { s_[q] = __shfl(sl, j + q); w_[q] = __shfl(wl, j + q); }
#pragma unroll
                for (int q = 0; q < 8; ++q) u_[q] = zu[(size_t)s_[q] * 48 + l];
#pragma unroll
                for (int q = 0; q < 8; q += 2) {
                    a0a = fmaf(w_[q], b2f(u_[q] & 0xFFFFu), a0a);
                    a1a = fmaf(w_[q], b2f(u_[q] >> 16), a1a);
                    a0b = fmaf(w_[q + 1], b2f(u_[q + 1] & 0xFFFFu), a0b);
                    a1b = fmaf(w_[q + 1], b2f(u_[q + 1] >> 16), a1b);
                }
            }
            if (j < m) {
                int rem = m - j;
                int s_[8]; float w_[8]; u32 u_[8];
#pragma unroll
                for (int q = 0; q < 8; ++q) {
                    int jj = j + (q < rem ? q : 0);
                    s_[q] = __shfl(sl, jj); w_[q] = __shfl(wl, jj);
                }
#pragma unroll
                for (int q = 0; q < 8; ++q) u_[q] = (q < rem) ? zu[(size_t)s_[q] * 48 + l] : 0u;
#pragma unroll
                for (int q = 0; q < 8; q += 2) {
                    float wa = (q < rem) ? w_[q] : 0.f;
                    float wb = (q + 1 < rem) ? w_[q + 1] : 0.f;
                    a0a = fmaf(wa, b2f(u_[q] & 0xFFFFu), a0a);
                    a1a = fmaf(wa, b2f(u_[q] >> 16), a1a);
                    a0b = fmaf(wb, b2f(u_[q + 1] & 0xFFFFu), a0b);
                    a1b = fmaf(wb, b2f(u_[q + 1] >> 16), a1b);
                }
            }
        }
        float h0 = fmaf(dn, a0a + a0b, b0);
        float h1 = fmaf(dn, a1a + a1b, b1);
        if (act) {
            u32 pk = (u32)f2b(h0) | ((u32)f2b(h1) << 16);
            ((u32*)H)[(size_t)n * 48 + l] = pk;
            lsum0 += h0; lsq0 = fmaf(h0, h0, lsq0);
            lsum1 += h1; lsq1 = fmaf(h1, h1, lsq1);
        }
        n = n2; e0 = e0n; e1 = e1n; pr = prn;
    }
    if (act) {
        atomicAdd(&ssum[2 * l], lsum0); atomicAdd(&ssq[2 * l], lsq0);
        atomicAdd(&ssum[2 * l + 1], lsum1); atomicAdd(&ssq[2 * l + 1], lsq1);
    }
    __syncthreads();
    if (tid < 96) { atomicAdd(&gsum[tid], ssum[tid]); atomicAdd(&gsq[tid], ssq[tid]); }
}

__global__ void k_bncoef(const float* __restrict__ gsum, const float* __restrict__ gsq,
                         const float* __restrict__ g, const float* __restrict__ be,
                         float* __restrict__ bnA, float* __restrict__ bnC) {
    int c = threadIdx.x;
    if (c < 96) {
        float mean = gsum[c] * (1.f / NN);
        float var = gsq[c] * (1.f / NN) - mean * mean;
        float inv = rsqrtf(var + BN_EPS);
        float a = g[c] * inv;
        bnA[c] = a;
        bnC[c] = fmaf(-a, mean, be[c]);
    }
}

// ---------------------------------------------------------------- final agg + log_softmax
// 4 nodes per wave; 16-lane group per node; lane pair-channels (2sl, 2sl+1). unroll 8.
__global__ __launch_bounds__(256) void k_agg32_lsm(const u16* __restrict__ Z,
                                                   float* __restrict__ Out,
                                                   const float* __restrict__ bias,
                                                   const int* __restrict__ row_start,
                                                   const int2* __restrict__ ewt,
                                                   const float* __restrict__ dinv) {
    int tid = threadIdx.x;
    int wid = tid >> 6, lane = tid & 63;
    int g = lane >> 4, sl = lane & 15;
    const u32* zu = (const u32*)Z;  // row stride 16 dwords
    float b0 = bias[2 * sl], b1 = bias[2 * sl + 1];
    int stride = gridDim.x * 16;
    for (int n0 = (blockIdx.x * 4 + wid) * 4; n0 < NN; n0 += stride) {
        int n = n0 + g;
        bool vn = n < NN;
        float dn = vn ? dinv[n] : 0.f;
        u32 uself = vn ? zu[(size_t)n * 16 + sl] : 0;
        float a0a = dn * b2f(uself & 0xFFFFu);
        float a1a = dn * b2f(uself >> 16);
        float a0b = 0.f, a1b = 0.f;
        int e0 = vn ? row_start[n] : 0, e1 = vn ? row_start[n + 1] : 0;
        for (int eb = e0; eb < e1; eb += 16) {
            int m = e1 - eb; if (m > 16) m = 16;
            int idx = eb + sl;
            int2 pr = (idx < e1) ? ewt[idx] : make_int2(0, 0);
            int slv = pr.x; float wlv = __int_as_float(pr.y);
            int j = 0;
            for (; j + 8 <= m; j += 8) {
                int s_[8]; float w_[8]; u32 u_[8];
#pragma unroll
                for (int q = 0; q < 8; ++q) { s_[q] = __shfl(slv, j + q, 16); w_[q] = __shfl(wlv, j + q, 16); }
#pragma unroll
                for (int q = 0; q < 8; ++q) u_[q] = zu[(size_t)s_[q] * 16 + sl];
#pragma unroll
                for (int q = 0; q < 8; q += 2) {
                    a0a = fmaf(w_[q], b2f(u_[q] & 0xFFFFu), a0a);
                    a1a = fmaf(w_[q], b2f(u_[q] >> 16), a1a);
                    a0b = fmaf(w_[q + 1], b2f(u_[q + 1] & 0xFFFFu), a0b);
                    a1b = fmaf(w_[q + 1], b2f(u_[q + 1] >> 16), a1b);
                }
            }
            for (; j < m; ++j) {
                int s = __shfl(slv, j, 16);
                float w = __shfl(wlv, j, 16);
                u32 u = zu[(size_t)s * 16 + sl];
                a0a = fmaf(w, b2f(u & 0xFFFFu), a0a);
                a1a = fmaf(w, b2f(u >> 16), a1a);
            }
        }
        float v0 = fmaf(dn, a0a + a0b, b0);
        float v1 = fmaf(dn, a1a + a1b, b1);
        float mx = fmaxf(v0, v1);
#pragma unroll
        for (int off = 8; off; off >>= 1) mx = fmaxf(mx, __shfl_xor(mx, off, 16));
        float ex = __expf(v0 - mx) + __expf(v1 - mx);
#pragma unroll
        for (int off = 8; off; off >>= 1) ex += __shfl_xor(ex, off, 16);
        float lse = mx + __logf(ex);
        if (vn) {
            float2 o = make_float2(v0 - lse, v1 - lse);
            *(float2*)&Out[(size_t)n * 32 + 2 * sl] = o;
        }
    }
}

// ---------------------------------------------------------------- launch

extern "C" void kernel_launch(void* const* d_in, const int* in_sizes, int n_in,
                              void* d_out, int out_size, void* d_ws, size_t ws_size,
                              hipStream_t stream) {
    const float* x  = (const float*)d_in[0];
    const int* ei   = (const int*)d_in[1];   // [2, NE]: src then dst
    const float* W1 = (const float*)d_in[2];
    const float* b1 = (const float*)d_in[3];
    const float* W2 = (const float*)d_in[4];
    const float* b2 = (const float*)d_in[5];
    const float* W3 = (const float*)d_in[6];
    const float* b3 = (const float*)d_in[7];
    const float* g1 = (const float*)d_in[8];
    const float* be1 = (const float*)d_in[9];
    const float* g2 = (const float*)d_in[10];
    const float* be2 = (const float*)d_in[11];
    float* out = (float*)d_out;

    const int* src = ei;
    const int* dst = ei + NE;

    char* p = (char*)d_ws;
    size_t off = 0;
    auto take = [&](size_t bytes) {
        char* r = p + off;
        off = (off + bytes + 255) & ~(size_t)255;
        return r;
    };
    float* dinv      = (float*)take(NN * 4);
    int*   deg       = (int*)take(NN * 4);
    int*   row_start = (int*)take((NN + 1) * 4);
    int*   cursor    = (int*)take(NN * 4);
    int*   blksum    = (int*)take(SCAN_NB * 4);
    int2*  ewt       = (int2*)take((size_t)NE * 8);
    float* meta      = (float*)take(768 * 4);
    u16*   bufA      = (u16*)take((size_t)NN * HID * 2);
    u16*   bufB      = (u16*)take((size_t)NN * HID * 2);

    float* sum1 = meta + 0,   *sq1 = meta + 96;
    float* sum2 = meta + 192, *sq2 = meta + 288;
    float* bnA1 = meta + 384, *bnC1 = meta + 480;
    float* bnA2 = meta + 576, *bnC2 = meta + 672;

    hipMemsetAsync(deg, 0, NN * 4, stream);
    hipMemsetAsync(cursor, 0, NN * 4, stream);
    hipMemsetAsync(meta, 0, 384 * 4, stream);  // sums/sumsqs

    const int EB = (NE + 255) / 256;
    const int VB = (NN + 255) / 256;
    k_hist<<<EB, 256, 0, stream>>>(dst, deg);
    k_dinv<<<VB, 256, 0, stream>>>(deg, dinv);
    k_scan1<<<SCAN_NB, 256, 0, stream>>>(deg, row_start, blksum);
    k_scan2<<<1, 512, 0, stream>>>(blksum, row_start);
    k_scan3<<<SCAN_NB, 256, 0, stream>>>(row_start, blksum);
    k_scatter<<<EB, 256, 0, stream>>>(src, dst, row_start, cursor, dinv, ewt);

    const int GB = (NN + 63) / 64;  // 1563 GEMM blocks
    const int AB = 2560;            // agg blocks (grid-stride)

    // layer 1: z = x@W1 ; h1 = agg(z)+b1 (+stats)
    k_gemm<DIN, HID, false, float><<<GB, 256, 0, stream>>>(x, W1, bufA, nullptr, nullptr, NN);
    k_agg96<<<AB, 256, 0, stream>>>(bufA, bufB, b1, row_start, ewt, dinv, sum1, sq1);
    k_bncoef<<<1, 128, 0, stream>>>(sum1, sq1, g1, be1, bnA1, bnC1);

    // layer 2: z = relu(bn(h1))@W2 ; h2 = agg(z)+b2 (+stats)
    k_gemm<HID, HID, true, u16><<<GB, 256, 0, stream>>>(bufB, W2, bufA, bnA1, bnC1, NN);
    k_agg96<<<AB, 256, 0, stream>>>(bufA, bufB, b2, row_start, ewt, dinv, sum2, sq2);
    k_bncoef<<<1, 128, 0, stream>>>(sum2, sq2, g2, be2, bnA2, bnC2);

    // layer 3: z = relu(bn(h2))@W3 ; out = log_softmax(agg(z)+b3)
    k_gemm<HID, DOUT, true, u16><<<GB, 256, 0, stream>>>(bufB, W3, bufA, bnA2, bnC2, NN);
    k_agg32_lsm<<<AB, 256, 0, stream>>>(bufA, out, b3, row_start, ewt, dinv);

    (void)in_sizes; (void)n_in; (void)out_size; (void)ws_size;
}

// Round 6
// 518.832 us; speedup vs baseline: 1.7995x; 1.0887x over previous
//
#include <hip/hip_runtime.h>
#include <cstddef>

#define NN 100000
#define NE 800000
#define DIN 128
#define HID 96
#define DOUT 32
static constexpr float BN_EPS = 1e-5f;
#define SCAN_NB ((NN + 255) / 256)   // 391

typedef unsigned short u16;
typedef unsigned int u32;

__device__ __forceinline__ float b2f(u32 lo16) {
    union { u32 u; float f; } c; c.u = lo16 << 16; return c.f;
}
__device__ __forceinline__ u16 f2b(float f) {
    union { float f; u32 u; } c; c.f = f;
    return (u16)((c.u + 0x7FFFu + ((c.u >> 16) & 1u)) >> 16);
}

// ---------------------------------------------------------------- setup kernels

__global__ void k_init(int* __restrict__ deg, int* __restrict__ cursor,
                       float* __restrict__ meta) {
    int i = blockIdx.x * 256 + threadIdx.x;
    if (i < NN) { deg[i] = 0; cursor[i] = 0; }
    if (i < 384) meta[i] = 0.f;
}

__global__ void k_hist(const int* __restrict__ dst, int* __restrict__ deg) {
    int e = blockIdx.x * blockDim.x + threadIdx.x;
    if (e < NE) atomicAdd(&deg[dst[e]], 1);
}

// scan phase 1 + dinv fused (reads deg anyway)
__global__ __launch_bounds__(256) void k_scan1(const int* __restrict__ deg,
                                               int* __restrict__ row_start,
                                               int* __restrict__ blksum,
                                               float* __restrict__ dinv) {
    __shared__ int lds[256];
    int t = threadIdx.x;
    int i = blockIdx.x * 256 + t;
    int v = (i < NN) ? deg[i] : 0;
    if (i < NN) dinv[i] = rsqrtf((float)(v + 1));  // +1 self-loop
    lds[t] = v;
    __syncthreads();
#pragma unroll
    for (int off = 1; off < 256; off <<= 1) {
        int add = (t >= off) ? lds[t - off] : 0;
        __syncthreads();
        lds[t] += add;
        __syncthreads();
    }
    if (i < NN) row_start[i] = lds[t] - v;  // exclusive
    if (t == 255) blksum[blockIdx.x] = lds[255];
}

__global__ __launch_bounds__(512) void k_scan2(int* __restrict__ blksum,
                                               int* __restrict__ row_start) {
    __shared__ int lds[512];
    int t = threadIdx.x;
    int v = (t < SCAN_NB) ? blksum[t] : 0;
    lds[t] = v;
    __syncthreads();
#pragma unroll
    for (int off = 1; off < 512; off <<= 1) {
        int add = (t >= off) ? lds[t - off] : 0;
        __syncthreads();
        lds[t] += add;
        __syncthreads();
    }
    if (t < SCAN_NB) blksum[t] = lds[t] - v;  // exclusive block offset
    if (t == 511) row_start[NN] = lds[511];   // grand total (= NE)
}

__global__ __launch_bounds__(256) void k_scan3(int* __restrict__ row_start,
                                               const int* __restrict__ blksum) {
    int i = blockIdx.x * 256 + threadIdx.x;
    if (i < NN) row_start[i] += blksum[blockIdx.x];
}

__global__ void k_scatter(const int* __restrict__ src, const int* __restrict__ dst,
                          const int* __restrict__ row_start, int* __restrict__ cursor,
                          const float* __restrict__ dinv,
                          int2* __restrict__ ewt) {
    int e = blockIdx.x * blockDim.x + threadIdx.x;
    if (e < NE) {
        int d = dst[e];
        int p = row_start[d] + atomicAdd(&cursor[d], 1);
        int s = src[e];
        ewt[p] = make_int2(s, __float_as_int(dinv[s]));
    }
}

// ---------------------------------------------------------------- GEMM (fp32 vector)
// Z[M x ND](bf16) = f(X)[M x KD] @ W[KD x ND], f = optional relu(a*x+c) per K-channel
// 128-row tile, 8x6 (or 8x2) register tile per thread: 14 LDS reads / 48 fma per kk.
template <int KD, int ND, bool FUSE, typename XT>
__global__ __launch_bounds__(256) void k_gemm(const XT* __restrict__ X,
                                              const float* __restrict__ W,
                                              u16* __restrict__ Z,
                                              const float* __restrict__ bnA,
                                              const float* __restrict__ bnC, int M) {
    constexpr int BK = 32;
    constexpr int CT = 16;
    constexpr int CPT = ND / CT;   // 6 (ND=96) or 2 (ND=32)
    constexpr int RPT = 8;         // 16 row-threads * 8 = 128 rows
    __shared__ float Xs[128 * 33];
    __shared__ float Ws[BK * ND];
    __shared__ float As[KD], Cs[KD];

    int tid = threadIdx.x;
    if (FUSE && tid < KD) { As[tid] = bnA[tid]; Cs[tid] = bnC[tid]; }
    int row0 = blockIdx.x * 128;
    int ct = tid % CT, rt = tid / CT;
    float acc[RPT][CPT];
#pragma unroll
    for (int r = 0; r < RPT; ++r)
#pragma unroll
        for (int c = 0; c < CPT; ++c) acc[r][c] = 0.f;

    for (int k0 = 0; k0 < KD; k0 += BK) {
        __syncthreads();
        if constexpr (sizeof(XT) == 4) {
            // fp32: float4/thread, 4 passes of 32 rows
#pragma unroll
            for (int pass = 0; pass < 4; ++pass) {
                int r = pass * 32 + (tid >> 3);
                int kq = (tid & 7) * 4;
                int grow = row0 + r;
                float4 v = make_float4(0.f, 0.f, 0.f, 0.f);
                if (grow < M) v = *(const float4*)&X[(size_t)grow * KD + k0 + kq];
                if (FUSE) {
                    v.x = fmaxf(fmaf(As[k0 + kq + 0], v.x, Cs[k0 + kq + 0]), 0.f);
                    v.y = fmaxf(fmaf(As[k0 + kq + 1], v.y, Cs[k0 + kq + 1]), 0.f);
                    v.z = fmaxf(fmaf(As[k0 + kq + 2], v.z, Cs[k0 + kq + 2]), 0.f);
                    v.w = fmaxf(fmaf(As[k0 + kq + 3], v.w, Cs[k0 + kq + 3]), 0.f);
                }
                Xs[r * 33 + kq + 0] = v.x;
                Xs[r * 33 + kq + 1] = v.y;
                Xs[r * 33 + kq + 2] = v.z;
                Xs[r * 33 + kq + 3] = v.w;
            }
        } else {
            // bf16: uint4 = 8 elems/thread, 4 threads/row, 2 passes of 64 rows
#pragma unroll
            for (int pass = 0; pass < 2; ++pass) {
                int r = pass * 64 + (tid >> 2);
                int kq = (tid & 3) * 8;
                int grow = row0 + r;
                uint4 v = make_uint4(0, 0, 0, 0);
                if (grow < M) v = *(const uint4*)&X[(size_t)grow * KD + k0 + kq];
                u32 w[4] = {v.x, v.y, v.z, v.w};
#pragma unroll
                for (int q = 0; q < 4; ++q) {
                    float lo = b2f(w[q] & 0xFFFFu);
                    float hi = b2f(w[q] >> 16);
                    if (FUSE) {
                        lo = fmaxf(fmaf(As[k0 + kq + 2 * q + 0], lo, Cs[k0 + kq + 2 * q + 0]), 0.f);
                        hi = fmaxf(fmaf(As[k0 + kq + 2 * q + 1], hi, Cs[k0 + kq + 2 * q + 1]), 0.f);
                    }
                    Xs[r * 33 + kq + 2 * q + 0] = lo;
                    Xs[r * 33 + kq + 2 * q + 1] = hi;
                }
            }
        }
#pragma unroll
        for (int f = tid; f < BK * ND / 4; f += 256) {
            int kk = f / (ND / 4);
            int c4 = (f % (ND / 4)) * 4;
            *(float4*)&Ws[kk * ND + c4] = *(const float4*)&W[(size_t)(k0 + kk) * ND + c4];
        }
        __syncthreads();
#pragma unroll
        for (int kk = 0; kk < BK; ++kk) {
            float xr[RPT];
#pragma unroll
            for (int r = 0; r < RPT; ++r) xr[r] = Xs[(rt * RPT + r) * 33 + kk];
            float wc[CPT];
#pragma unroll
            for (int c = 0; c < CPT; ++c) wc[c] = Ws[kk * ND + ct * CPT + c];
#pragma unroll
            for (int r = 0; r < RPT; ++r)
#pragma unroll
                for (int c = 0; c < CPT; ++c) acc[r][c] = fmaf(xr[r], wc[c], acc[r][c]);
        }
    }
#pragma unroll
    for (int r = 0; r < RPT; ++r) {
        int grow = row0 + rt * RPT + r;
        if (grow < M) {
#pragma unroll
            for (int c = 0; c < CPT; c += 2) {
                u32 pk = (u32)f2b(acc[r][c]) | ((u32)f2b(acc[r][c + 1]) << 16);
                *(u32*)&Z[(size_t)grow * ND + ct * CPT + c] = pk;
            }
        }
    }
}

// ---------------------------------------------------------------- aggregation, 96ch (bf16)
__global__ __launch_bounds__(256) void k_agg96(const u16* __restrict__ Z,
                                               u16* __restrict__ H,
                                               const float* __restrict__ bias,
                                               const int* __restrict__ row_start,
                                               const int2* __restrict__ ewt,
                                               const float* __restrict__ dinv,
                                               float* __restrict__ gsum,
                                               float* __restrict__ gsq) {
    __shared__ float ssum[96], ssq[96];
    int tid = threadIdx.x;
    if (tid < 96) { ssum[tid] = 0.f; ssq[tid] = 0.f; }
    __syncthreads();
    int wid = tid >> 6, lane = tid & 63;
    bool act = lane < 48;
    int l = act ? lane : 47;
    const u32* zu = (const u32*)Z;          // row stride 48 dwords
    float b0 = bias[2 * l], b1 = bias[2 * l + 1];
    float lsum0 = 0.f, lsq0 = 0.f, lsum1 = 0.f, lsq1 = 0.f;
    const int stride = gridDim.x * 4;

    int n = blockIdx.x * 4 + wid;
    int e0 = 0, e1 = 0;
    int2 pr = make_int2(0, 0);
    if (n < NN) {
        e0 = row_start[n]; e1 = row_start[n + 1];
        if (e0 + lane < e1) pr = ewt[e0 + lane];
    }
    while (n < NN) {
        int n2 = n + stride;
        int e0n = 0, e1n = 0;
        if (n2 < NN) { e0n = row_start[n2]; e1n = row_start[n2 + 1]; }

        float dn = dinv[n];
        u32 uself = zu[(size_t)n * 48 + l];
        float a0a = dn * b2f(uself & 0xFFFFu);
        float a1a = dn * b2f(uself >> 16);
        float a0b = 0.f, a1b = 0.f;

        int sl = pr.x; float wl = __int_as_float(pr.y);

        int2 prn = make_int2(0, 0);
        if (n2 < NN && e0n + lane < e1n) prn = ewt[e0n + lane];

        for (int eb = e0; eb < e1; eb += 64) {
            if (eb != e0) {  // rare: deg > 64
                int idx = eb + lane;
                int2 p2 = (idx < e1) ? ewt[idx] : make_int2(0, 0);
                sl = p2.x; wl = __int_as_float(p2.y);
            }
            int m = e1 - eb; if (m > 64) m = 64;
            int j = 0;
            for (; j + 8 <= m; j += 8) {
                int s_[8]; float w_[8]; u32 u_[8];
#pragma unroll
                for (int q = 0; q < 8; ++q) { s_[q] = __shfl(sl, j + q); w_[q] = __shfl(wl, j + q); }
#pragma unroll
                for (int q = 0; q < 8; ++q) u_[q] = zu[(size_t)s_[q] * 48 + l];
#pragma unroll
                for (int q = 0; q < 8; q += 2) {
                    a0a = fmaf(w_[q], b2f(u_[q] & 0xFFFFu), a0a);
                    a1a = fmaf(w_[q], b2f(u_[q] >> 16), a1a);
                    a0b = fmaf(w_[q + 1], b2f(u_[q + 1] & 0xFFFFu), a0b);
                    a1b = fmaf(w_[q + 1], b2f(u_[q + 1] >> 16), a1b);
                }
            }
            if (j < m) {
                int rem = m - j;
                int s_[8]; float w_[8]; u32 u_[8];
#pragma unroll
                for (int q = 0; q < 8; ++q) {
                    int jj = j + (q < rem ? q : 0);
                    s_[q] = __shfl(sl, jj); w_[q] = __shfl(wl, jj);
                }
#pragma unroll
                for (int q = 0; q < 8; ++q) u_[q] = (q < rem) ? zu[(size_t)s_[q] * 48 + l] : 0u;
#pragma unroll
                for (int q = 0; q < 8; q += 2) {
                    float wa = (q < rem) ? w_[q] : 0.f;
                    float wb = (q + 1 < rem) ? w_[q + 1] : 0.f;
                    a0a = fmaf(wa, b2f(u_[q] & 0xFFFFu), a0a);
                    a1a = fmaf(wa, b2f(u_[q] >> 16), a1a);
                    a0b = fmaf(wb, b2f(u_[q + 1] & 0xFFFFu), a0b);
                    a1b = fmaf(wb, b2f(u_[q + 1] >> 16), a1b);
                }
            }
        }
        float h0 = fmaf(dn, a0a + a0b, b0);
        float h1 = fmaf(dn, a1a + a1b, b1);
        if (act) {
            u32 pk = (u32)f2b(h0) | ((u32)f2b(h1) << 16);
            ((u32*)H)[(size_t)n * 48 + l] = pk;
            lsum0 += h0; lsq0 = fmaf(h0, h0, lsq0);
            lsum1 += h1; lsq1 = fmaf(h1, h1, lsq1);
        }
        n = n2; e0 = e0n; e1 = e1n; pr = prn;
    }
    if (act) {
        atomicAdd(&ssum[2 * l], lsum0); atomicAdd(&ssq[2 * l], lsq0);
        atomicAdd(&ssum[2 * l + 1], lsum1); atomicAdd(&ssq[2 * l + 1], lsq1);
    }
    __syncthreads();
    if (tid < 96) { atomicAdd(&gsum[tid], ssum[tid]); atomicAdd(&gsq[tid], ssq[tid]); }
}

__global__ void k_bncoef(const float* __restrict__ gsum, const float* __restrict__ gsq,
                         const float* __restrict__ g, const float* __restrict__ be,
                         float* __restrict__ bnA, float* __restrict__ bnC) {
    int c = threadIdx.x;
    if (c < 96) {
        float mean = gsum[c] * (1.f / NN);
        float var = gsq[c] * (1.f / NN) - mean * mean;
        float inv = rsqrtf(var + BN_EPS);
        float a = g[c] * inv;
        bnA[c] = a;
        bnC[c] = fmaf(-a, mean, be[c]);
    }
}

// ---------------------------------------------------------------- final agg + log_softmax
__global__ __launch_bounds__(256) void k_agg32_lsm(const u16* __restrict__ Z,
                                                   float* __restrict__ Out,
                                                   const float* __restrict__ bias,
                                                   const int* __restrict__ row_start,
                                                   const int2* __restrict__ ewt,
                                                   const float* __restrict__ dinv) {
    int tid = threadIdx.x;
    int wid = tid >> 6, lane = tid & 63;
    int g = lane >> 4, sl = lane & 15;
    const u32* zu = (const u32*)Z;  // row stride 16 dwords
    float b0 = bias[2 * sl], b1 = bias[2 * sl + 1];
    int stride = gridDim.x * 16;
    for (int n0 = (blockIdx.x * 4 + wid) * 4; n0 < NN; n0 += stride) {
        int n = n0 + g;
        bool vn = n < NN;
        float dn = vn ? dinv[n] : 0.f;
        u32 uself = vn ? zu[(size_t)n * 16 + sl] : 0;
        float a0a = dn * b2f(uself & 0xFFFFu);
        float a1a = dn * b2f(uself >> 16);
        float a0b = 0.f, a1b = 0.f;
        int e0 = vn ? row_start[n] : 0, e1 = vn ? row_start[n + 1] : 0;
        for (int eb = e0; eb < e1; eb += 16) {
            int m = e1 - eb; if (m > 16) m = 16;
            int idx = eb + sl;
            int2 pr = (idx < e1) ? ewt[idx] : make_int2(0, 0);
            int slv = pr.x; float wlv = __int_as_float(pr.y);
            int j = 0;
            for (; j + 8 <= m; j += 8) {
                int s_[8]; float w_[8]; u32 u_[8];
#pragma unroll
                for (int q = 0; q < 8; ++q) { s_[q] = __shfl(slv, j + q, 16); w_[q] = __shfl(wlv, j + q, 16); }
#pragma unroll
                for (int q = 0; q < 8; ++q) u_[q] = zu[(size_t)s_[q] * 16 + sl];
#pragma unroll
                for (int q = 0; q < 8; q += 2) {
                    a0a = fmaf(w_[q], b2f(u_[q] & 0xFFFFu), a0a);
                    a1a = fmaf(w_[q], b2f(u_[q] >> 16), a1a);
                    a0b = fmaf(w_[q + 1], b2f(u_[q + 1] & 0xFFFFu), a0b);
                    a1b = fmaf(w_[q + 1], b2f(u_[q + 1] >> 16), a1b);
                }
            }
            for (; j < m; ++j) {
                int s = __shfl(slv, j, 16);
                float w = __shfl(wlv, j, 16);
                u32 u = zu[(size_t)s * 16 + sl];
                a0a = fmaf(w, b2f(u & 0xFFFFu), a0a);
                a1a = fmaf(w, b2f(u >> 16), a1a);
            }
        }
        float v0 = fmaf(dn, a0a + a0b, b0);
        float v1 = fmaf(dn, a1a + a1b, b1);
        float mx = fmaxf(v0, v1);
#pragma unroll
        for (int off = 8; off; off >>= 1) mx = fmaxf(mx, __shfl_xor(mx, off, 16));
        float ex = __expf(v0 - mx) + __expf(v1 - mx);
#pragma unroll
        for (int off = 8; off; off >>= 1) ex += __shfl_xor(ex, off, 16);
        float lse = mx + __logf(ex);
        if (vn) {
            float2 o = make_float2(v0 - lse, v1 - lse);
            *(float2*)&Out[(size_t)n * 32 + 2 * sl] = o;
        }
    }
}

// ---------------------------------------------------------------- launch

extern "C" void kernel_launch(void* const* d_in, const int* in_sizes, int n_in,
                              void* d_out, int out_size, void* d_ws, size_t ws_size,
                              hipStream_t stream) {
    const float* x  = (const float*)d_in[0];
    const int* ei   = (const int*)d_in[1];   // [2, NE]: src then dst
    const float* W1 = (const float*)d_in[2];
    const float* b1 = (const float*)d_in[3];
    const float* W2 = (const float*)d_in[4];
    const float* b2 = (const float*)d_in[5];
    const float* W3 = (const float*)d_in[6];
    const float* b3 = (const float*)d_in[7];
    const float* g1 = (const float*)d_in[8];
    const float* be1 = (const float*)d_in[9];
    const float* g2 = (const float*)d_in[10];
    const float* be2 = (const float*)d_in[11];
    float* out = (float*)d_out;

    const int* src = ei;
    const int* dst = ei + NE;

    char* p = (char*)d_ws;
    size_t off = 0;
    auto take = [&](size_t bytes) {
        char* r = p + off;
        off = (off + bytes + 255) & ~(size_t)255;
        return r;
    };
    float* dinv      = (float*)take(NN * 4);
    int*   deg       = (int*)take(NN * 4);
    int*   row_start = (int*)take((NN + 1) * 4);
    int*   cursor    = (int*)take(NN * 4);
    int*   blksum    = (int*)take(SCAN_NB * 4);
    int2*  ewt       = (int2*)take((size_t)NE * 8);
    float* meta      = (float*)take(768 * 4);
    u16*   bufA      = (u16*)take((size_t)NN * HID * 2);
    u16*   bufB      = (u16*)take((size_t)NN * HID * 2);

    float* sum1 = meta + 0,   *sq1 = meta + 96;
    float* sum2 = meta + 192, *sq2 = meta + 288;
    float* bnA1 = meta + 384, *bnC1 = meta + 480;
    float* bnA2 = meta + 576, *bnC2 = meta + 672;

    const int EB = (NE + 255) / 256;
    const int VB = (NN + 255) / 256;
    k_init<<<VB, 256, 0, stream>>>(deg, cursor, meta);
    k_hist<<<EB, 256, 0, stream>>>(dst, deg);
    k_scan1<<<SCAN_NB, 256, 0, stream>>>(deg, row_start, blksum, dinv);
    k_scan2<<<1, 512, 0, stream>>>(blksum, row_start);
    k_scan3<<<SCAN_NB, 256, 0, stream>>>(row_start, blksum);
    k_scatter<<<EB, 256, 0, stream>>>(src, dst, row_start, cursor, dinv, ewt);

    const int GB = (NN + 127) / 128;  // 782 GEMM blocks
    const int AB = 2560;              // agg blocks (grid-stride)

    // layer 1: z = x@W1 ; h1 = agg(z)+b1 (+stats)
    k_gemm<DIN, HID, false, float><<<GB, 256, 0, stream>>>(x, W1, bufA, nullptr, nullptr, NN);
    k_agg96<<<AB, 256, 0, stream>>>(bufA, bufB, b1, row_start, ewt, dinv, sum1, sq1);
    k_bncoef<<<1, 128, 0, stream>>>(sum1, sq1, g1, be1, bnA1, bnC1);

    // layer 2: z = relu(bn(h1))@W2 ; h2 = agg(z)+b2 (+stats)
    k_gemm<HID, HID, true, u16><<<GB, 256, 0, stream>>>(bufB, W2, bufA, bnA1, bnC1, NN);
    k_agg96<<<AB, 256, 0, stream>>>(bufA, bufB, b2, row_start, ewt, dinv, sum2, sq2);
    k_bncoef<<<1, 128, 0, stream>>>(sum2, sq2, g2, be2, bnA2, bnC2);

    // layer 3: z = relu(bn(h2))@W3 ; out = log_softmax(agg(z)+b3)
    k_gemm<HID, DOUT, true, u16><<<GB, 256, 0, stream>>>(bufB, W3, bufA, bnA2, bnC2, NN);
    k_agg32_lsm<<<AB, 256, 0, stream>>>(bufA, out, b3, row_start, ewt, dinv);

    (void)in_sizes; (void)n_in; (void)out_size; (void)ws_size;
}

// Round 7
// 484.585 us; speedup vs baseline: 1.9266x; 1.0707x over previous
//
#include <hip/hip_runtime.h>
#include <cstddef>

#define NN 100000
#define NE 800000
#define DIN 128
#define HID 96
#define DOUT 32
static constexpr float BN_EPS = 1e-5f;
#define SCAN_NB ((NN + 255) / 256)   // 391

typedef unsigned short u16;
typedef unsigned int u32;

__device__ __forceinline__ float b2f(u32 lo16) {
    union { u32 u; float f; } c; c.u = lo16 << 16; return c.f;
}
__device__ __forceinline__ u16 f2b(float f) {
    union { float f; u32 u; } c; c.f = f;
    return (u16)((c.u + 0x7FFFu + ((c.u >> 16) & 1u)) >> 16);
}

// ---------------------------------------------------------------- setup kernels

__global__ void k_init(int* __restrict__ deg, float* __restrict__ meta) {
    int i = blockIdx.x * 256 + threadIdx.x;
    if (i < NN) deg[i] = 0;
    if (i < 384) meta[i] = 0.f;
}

// histogram + per-edge rank (position of edge within its dst bucket)
__global__ void k_hist(const int* __restrict__ dst, int* __restrict__ deg,
                       int* __restrict__ rank) {
    int e = blockIdx.x * blockDim.x + threadIdx.x;
    if (e < NE) rank[e] = atomicAdd(&deg[dst[e]], 1);
}

// scan phase 1 + dinv fused
__global__ __launch_bounds__(256) void k_scan1(const int* __restrict__ deg,
                                               int* __restrict__ row_start,
                                               int* __restrict__ blksum,
                                               float* __restrict__ dinv) {
    __shared__ int lds[256];
    int t = threadIdx.x;
    int i = blockIdx.x * 256 + t;
    int v = (i < NN) ? deg[i] : 0;
    if (i < NN) dinv[i] = rsqrtf((float)(v + 1));  // +1 self-loop
    lds[t] = v;
    __syncthreads();
#pragma unroll
    for (int off = 1; off < 256; off <<= 1) {
        int add = (t >= off) ? lds[t - off] : 0;
        __syncthreads();
        lds[t] += add;
        __syncthreads();
    }
    if (i < NN) row_start[i] = lds[t] - v;  // exclusive
    if (t == 255) blksum[blockIdx.x] = lds[255];
}

__global__ __launch_bounds__(512) void k_scan2(int* __restrict__ blksum,
                                               int* __restrict__ row_start) {
    __shared__ int lds[512];
    int t = threadIdx.x;
    int v = (t < SCAN_NB) ? blksum[t] : 0;
    lds[t] = v;
    __syncthreads();
#pragma unroll
    for (int off = 1; off < 512; off <<= 1) {
        int add = (t >= off) ? lds[t - off] : 0;
        __syncthreads();
        lds[t] += add;
        __syncthreads();
    }
    if (t < SCAN_NB) blksum[t] = lds[t] - v;  // exclusive block offset
    if (t == 511) row_start[NN] = lds[511];   // grand total (= NE)
}

__global__ __launch_bounds__(256) void k_scan3(int* __restrict__ row_start,
                                               const int* __restrict__ blksum) {
    int i = blockIdx.x * 256 + threadIdx.x;
    if (i < NN) row_start[i] += blksum[blockIdx.x];
}

// atomic-free scatter: position = row_start[dst] + rank
__global__ void k_scatter(const int* __restrict__ src, const int* __restrict__ dst,
                          const int* __restrict__ row_start,
                          const int* __restrict__ rank,
                          const float* __restrict__ dinv,
                          int2* __restrict__ ewt) {
    int e = blockIdx.x * blockDim.x + threadIdx.x;
    if (e < NE) {
        int d = dst[e];
        int p = row_start[d] + rank[e];
        int s = src[e];
        ewt[p] = make_int2(s, __float_as_int(dinv[s]));
    }
}

// ---------------------------------------------------------------- GEMM (fp32 vector)
template <int KD, int ND, bool FUSE, typename XT>
__global__ __launch_bounds__(256) void k_gemm(const XT* __restrict__ X,
                                              const float* __restrict__ W,
                                              u16* __restrict__ Z,
                                              const float* __restrict__ bnA,
                                              const float* __restrict__ bnC, int M) {
    constexpr int BK = 32;
    constexpr int CT = 16;
    constexpr int CPT = ND / CT;   // 6 (ND=96) or 2 (ND=32)
    constexpr int RPT = 8;         // 16 row-threads * 8 = 128 rows
    __shared__ float Xs[128 * 33];
    __shared__ float Ws[BK * ND];
    __shared__ float As[KD], Cs[KD];

    int tid = threadIdx.x;
    if (FUSE && tid < KD) { As[tid] = bnA[tid]; Cs[tid] = bnC[tid]; }
    int row0 = blockIdx.x * 128;
    int ct = tid % CT, rt = tid / CT;
    float acc[RPT][CPT];
#pragma unroll
    for (int r = 0; r < RPT; ++r)
#pragma unroll
        for (int c = 0; c < CPT; ++c) acc[r][c] = 0.f;

    for (int k0 = 0; k0 < KD; k0 += BK) {
        __syncthreads();
        if constexpr (sizeof(XT) == 4) {
#pragma unroll
            for (int pass = 0; pass < 4; ++pass) {
                int r = pass * 32 + (tid >> 3);
                int kq = (tid & 7) * 4;
                int grow = row0 + r;
                float4 v = make_float4(0.f, 0.f, 0.f, 0.f);
                if (grow < M) v = *(const float4*)&X[(size_t)grow * KD + k0 + kq];
                if (FUSE) {
                    v.x = fmaxf(fmaf(As[k0 + kq + 0], v.x, Cs[k0 + kq + 0]), 0.f);
                    v.y = fmaxf(fmaf(As[k0 + kq + 1], v.y, Cs[k0 + kq + 1]), 0.f);
                    v.z = fmaxf(fmaf(As[k0 + kq + 2], v.z, Cs[k0 + kq + 2]), 0.f);
                    v.w = fmaxf(fmaf(As[k0 + kq + 3], v.w, Cs[k0 + kq + 3]), 0.f);
                }
                Xs[r * 33 + kq + 0] = v.x;
                Xs[r * 33 + kq + 1] = v.y;
                Xs[r * 33 + kq + 2] = v.z;
                Xs[r * 33 + kq + 3] = v.w;
            }
        } else {
#pragma unroll
            for (int pass = 0; pass < 2; ++pass) {
                int r = pass * 64 + (tid >> 2);
                int kq = (tid & 3) * 8;
                int grow = row0 + r;
                uint4 v = make_uint4(0, 0, 0, 0);
                if (grow < M) v = *(const uint4*)&X[(size_t)grow * KD + k0 + kq];
                u32 w[4] = {v.x, v.y, v.z, v.w};
#pragma unroll
                for (int q = 0; q < 4; ++q) {
                    float lo = b2f(w[q] & 0xFFFFu);
                    float hi = b2f(w[q] >> 16);
                    if (FUSE) {
                        lo = fmaxf(fmaf(As[k0 + kq + 2 * q + 0], lo, Cs[k0 + kq + 2 * q + 0]), 0.f);
                        hi = fmaxf(fmaf(As[k0 + kq + 2 * q + 1], hi, Cs[k0 + kq + 2 * q + 1]), 0.f);
                    }
                    Xs[r * 33 + kq + 2 * q + 0] = lo;
                    Xs[r * 33 + kq + 2 * q + 1] = hi;
                }
            }
        }
#pragma unroll
        for (int f = tid; f < BK * ND / 4; f += 256) {
            int kk = f / (ND / 4);
            int c4 = (f % (ND / 4)) * 4;
            *(float4*)&Ws[kk * ND + c4] = *(const float4*)&W[(size_t)(k0 + kk) * ND + c4];
        }
        __syncthreads();
#pragma unroll
        for (int kk = 0; kk < BK; ++kk) {
            float xr[RPT];
#pragma unroll
            for (int r = 0; r < RPT; ++r) xr[r] = Xs[(rt * RPT + r) * 33 + kk];
            float wc[CPT];
#pragma unroll
            for (int c = 0; c < CPT; ++c) wc[c] = Ws[kk * ND + ct * CPT + c];
#pragma unroll
            for (int r = 0; r < RPT; ++r)
#pragma unroll
                for (int c = 0; c < CPT; ++c) acc[r][c] = fmaf(xr[r], wc[c], acc[r][c]);
        }
    }
#pragma unroll
    for (int r = 0; r < RPT; ++r) {
        int grow = row0 + rt * RPT + r;
        if (grow < M) {
#pragma unroll
            for (int c = 0; c < CPT; c += 2) {
                u32 pk = (u32)f2b(acc[r][c]) | ((u32)f2b(acc[r][c + 1]) << 16);
                *(u32*)&Z[(size_t)grow * ND + ct * CPT + c] = pk;
            }
        }
    }
}

// ---------------------------------------------------------------- aggregation, 96ch (bf16)
// one wave per node; lane l<48 gathers the row's dword l. Two-chunk software pipeline:
// chunk c+1's 8 gathers issue while chunk c's fma runs -> up to 16 outstanding.
__global__ __launch_bounds__(256) void k_agg96(const u16* __restrict__ Z,
                                               u16* __restrict__ H,
                                               const float* __restrict__ bias,
                                               const int* __restrict__ row_start,
                                               const int2* __restrict__ ewt,
                                               const float* __restrict__ dinv,
                                               float* __restrict__ gsum,
                                               float* __restrict__ gsq) {
    __shared__ float ssum[96], ssq[96];
    int tid = threadIdx.x;
    if (tid < 96) { ssum[tid] = 0.f; ssq[tid] = 0.f; }
    __syncthreads();
    int wid = tid >> 6, lane = tid & 63;
    bool act = lane < 48;
    int l = act ? lane : 47;
    const u32* zu = (const u32*)Z;          // row stride 48 dwords
    float b0 = bias[2 * l], b1 = bias[2 * l + 1];
    float lsum0 = 0.f, lsq0 = 0.f, lsum1 = 0.f, lsq1 = 0.f;
    const int stride = gridDim.x * 4;

    int n = blockIdx.x * 4 + wid;
    int e0 = 0, e1 = 0;
    int2 pr = make_int2(0, 0);
    if (n < NN) {
        e0 = row_start[n]; e1 = row_start[n + 1];
        if (e0 + lane < e1) pr = ewt[e0 + lane];
    }
    while (n < NN) {
        int n2 = n + stride;
        int e0n = 0, e1n = 0;
        if (n2 < NN) { e0n = row_start[n2]; e1n = row_start[n2 + 1]; }

        float dn = dinv[n];
        u32 uself = zu[(size_t)n * 48 + l];
        float a0a = dn * b2f(uself & 0xFFFFu);
        float a1a = dn * b2f(uself >> 16);
        float a0b = 0.f, a1b = 0.f;

        int sl = pr.x; float wl = __int_as_float(pr.y);

        int2 prn = make_int2(0, 0);
        if (n2 < NN && e0n + lane < e1n) prn = ewt[e0n + lane];

        int m = e1 - e0;
        if (m <= 64) {
            // pipelined: chunks of 8, one chunk lookahead
            int K = (m + 7) >> 3;
            u32 uA[8], uB[8];
            float wA[8], wB[8];
            // load chunk 0 -> A
            {
#pragma unroll
                for (int q = 0; q < 8; ++q) {
                    int j = q;
                    bool v = j < m;
                    int s = __shfl(sl, v ? j : 0);
                    wA[q] = v ? __shfl(wl, j) : 0.f;
                    uA[q] = zu[(size_t)s * 48 + l];
                }
            }
            for (int c = 0; c < K; ++c) {
                if ((c & 1) == 0) {
                    if (c + 1 < K) {
#pragma unroll
                        for (int q = 0; q < 8; ++q) {
                            int j = (c + 1) * 8 + q;
                            bool v = j < m;
                            int s = __shfl(sl, v ? j : 0);
                            wB[q] = v ? __shfl(wl, j) : 0.f;
                            uB[q] = zu[(size_t)s * 48 + l];
                        }
                    }
#pragma unroll
                    for (int q = 0; q < 8; q += 2) {
                        a0a = fmaf(wA[q], b2f(uA[q] & 0xFFFFu), a0a);
                        a1a = fmaf(wA[q], b2f(uA[q] >> 16), a1a);
                        a0b = fmaf(wA[q + 1], b2f(uA[q + 1] & 0xFFFFu), a0b);
                        a1b = fmaf(wA[q + 1], b2f(uA[q + 1] >> 16), a1b);
                    }
                } else {
                    if (c + 1 < K) {
#pragma unroll
                        for (int q = 0; q < 8; ++q) {
                            int j = (c + 1) * 8 + q;
                            bool v = j < m;
                            int s = __shfl(sl, v ? j : 0);
                            wA[q] = v ? __shfl(wl, j) : 0.f;
                            uA[q] = zu[(size_t)s * 48 + l];
                        }
                    }
#pragma unroll
                    for (int q = 0; q < 8; q += 2) {
                        a0a = fmaf(wB[q], b2f(uB[q] & 0xFFFFu), a0a);
                        a1a = fmaf(wB[q], b2f(uB[q] >> 16), a1a);
                        a0b = fmaf(wB[q + 1], b2f(uB[q + 1] & 0xFFFFu), a0b);
                        a1b = fmaf(wB[q + 1], b2f(uB[q + 1] >> 16), a1b);
                    }
                }
            }
        } else {
            // rare: deg > 64, windowed fallback
            for (int eb = e0; eb < e1; eb += 64) {
                if (eb != e0) {
                    int idx = eb + lane;
                    int2 p2 = (idx < e1) ? ewt[idx] : make_int2(0, 0);
                    sl = p2.x; wl = __int_as_float(p2.y);
                }
                int mm = e1 - eb; if (mm > 64) mm = 64;
                for (int j = 0; j < mm; ++j) {
                    int s = __shfl(sl, j);
                    float w = __shfl(wl, j);
                    u32 u = zu[(size_t)s * 48 + l];
                    a0a = fmaf(w, b2f(u & 0xFFFFu), a0a);
                    a1a = fmaf(w, b2f(u >> 16), a1a);
                }
            }
        }
        float h0 = fmaf(dn, a0a + a0b, b0);
        float h1 = fmaf(dn, a1a + a1b, b1);
        if (act) {
            u32 pk = (u32)f2b(h0) | ((u32)f2b(h1) << 16);
            ((u32*)H)[(size_t)n * 48 + l] = pk;
            lsum0 += h0; lsq0 = fmaf(h0, h0, lsq0);
            lsum1 += h1; lsq1 = fmaf(h1, h1, lsq1);
        }
        n = n2; e0 = e0n; e1 = e1n; pr = prn;
    }
    if (act) {
        atomicAdd(&ssum[2 * l], lsum0); atomicAdd(&ssq[2 * l], lsq0);
        atomicAdd(&ssum[2 * l + 1], lsum1); atomicAdd(&ssq[2 * l + 1], lsq1);
    }
    __syncthreads();
    if (tid < 96) { atomicAdd(&gsum[tid], ssum[tid]); atomicAdd(&gsq[tid], ssq[tid]); }
}

__global__ void k_bncoef(const float* __restrict__ gsum, const float* __restrict__ gsq,
                         const float* __restrict__ g, const float* __restrict__ be,
                         float* __restrict__ bnA, float* __restrict__ bnC) {
    int c = threadIdx.x;
    if (c < 96) {
        float mean = gsum[c] * (1.f / NN);
        float var = gsq[c] * (1.f / NN) - mean * mean;
        float inv = rsqrtf(var + BN_EPS);
        float a = g[c] * inv;
        bnA[c] = a;
        bnC[c] = fmaf(-a, mean, be[c]);
    }
}

// ---------------------------------------------------------------- final agg + log_softmax
// 4 nodes per wave (16-lane groups). Full-window gather: all <=16 edges in flight.
__global__ __launch_bounds__(256) void k_agg32_lsm(const u16* __restrict__ Z,
                                                   float* __restrict__ Out,
                                                   const float* __restrict__ bias,
                                                   const int* __restrict__ row_start,
                                                   const int2* __restrict__ ewt,
                                                   const float* __restrict__ dinv) {
    int tid = threadIdx.x;
    int wid = tid >> 6, lane = tid & 63;
    int g = lane >> 4, sl = lane & 15;
    const u32* zu = (const u32*)Z;  // row stride 16 dwords
    float b0 = bias[2 * sl], b1 = bias[2 * sl + 1];
    int stride = gridDim.x * 16;
    for (int n0 = (blockIdx.x * 4 + wid) * 4; n0 < NN; n0 += stride) {
        int n = n0 + g;
        bool vn = n < NN;
        float dn = vn ? dinv[n] : 0.f;
        u32 uself = vn ? zu[(size_t)n * 16 + sl] : 0;
        float a0a = dn * b2f(uself & 0xFFFFu);
        float a1a = dn * b2f(uself >> 16);
        float a0b = 0.f, a1b = 0.f;
        int e0 = vn ? row_start[n] : 0, e1 = vn ? row_start[n + 1] : 0;
        for (int eb = e0; eb < e1; eb += 16) {
            int m = e1 - eb; if (m > 16) m = 16;
            int idx = eb + sl;
            int2 pr = (idx < e1) ? ewt[idx] : make_int2(0, 0);
            int slv = pr.x; float wlv = __int_as_float(pr.y);
            u32 u_[16]; float w_[16];
#pragma unroll
            for (int q = 0; q < 16; ++q) {
                bool v = q < m;
                int s = __shfl(slv, v ? q : 0, 16);
                w_[q] = v ? __shfl(wlv, q, 16) : 0.f;
                u_[q] = zu[(size_t)s * 16 + sl];
            }
#pragma unroll
            for (int q = 0; q < 16; q += 2) {
                a0a = fmaf(w_[q], b2f(u_[q] & 0xFFFFu), a0a);
                a1a = fmaf(w_[q], b2f(u_[q] >> 16), a1a);
                a0b = fmaf(w_[q + 1], b2f(u_[q + 1] & 0xFFFFu), a0b);
                a1b = fmaf(w_[q + 1], b2f(u_[q + 1] >> 16), a1b);
            }
        }
        float v0 = fmaf(dn, a0a + a0b, b0);
        float v1 = fmaf(dn, a1a + a1b, b1);
        float mx = fmaxf(v0, v1);
#pragma unroll
        for (int off = 8; off; off >>= 1) mx = fmaxf(mx, __shfl_xor(mx, off, 16));
        float ex = __expf(v0 - mx) + __expf(v1 - mx);
#pragma unroll
        for (int off = 8; off; off >>= 1) ex += __shfl_xor(ex, off, 16);
        float lse = mx + __logf(ex);
        if (vn) {
            float2 o = make_float2(v0 - lse, v1 - lse);
            *(float2*)&Out[(size_t)n * 32 + 2 * sl] = o;
        }
    }
}

// ---------------------------------------------------------------- launch

extern "C" void kernel_launch(void* const* d_in, const int* in_sizes, int n_in,
                              void* d_out, int out_size, void* d_ws, size_t ws_size,
                              hipStream_t stream) {
    const float* x  = (const float*)d_in[0];
    const int* ei   = (const int*)d_in[1];   // [2, NE]: src then dst
    const float* W1 = (const float*)d_in[2];
    const float* b1 = (const float*)d_in[3];
    const float* W2 = (const float*)d_in[4];
    const float* b2 = (const float*)d_in[5];
    const float* W3 = (const float*)d_in[6];
    const float* b3 = (const float*)d_in[7];
    const float* g1 = (const float*)d_in[8];
    const float* be1 = (const float*)d_in[9];
    const float* g2 = (const float*)d_in[10];
    const float* be2 = (const float*)d_in[11];
    float* out = (float*)d_out;

    const int* src = ei;
    const int* dst = ei + NE;

    char* p = (char*)d_ws;
    size_t off = 0;
    auto take = [&](size_t bytes) {
        char* r = p + off;
        off = (off + bytes + 255) & ~(size_t)255;
        return r;
    };
    float* dinv      = (float*)take(NN * 4);
    int*   deg       = (int*)take(NN * 4);
    int*   row_start = (int*)take((NN + 1) * 4);
    int*   blksum    = (int*)take(SCAN_NB * 4);
    int*   rank      = (int*)take((size_t)NE * 4);
    int2*  ewt       = (int2*)take((size_t)NE * 8);
    float* meta      = (float*)take(768 * 4);
    u16*   bufA      = (u16*)take((size_t)NN * HID * 2);
    u16*   bufB      = (u16*)take((size_t)NN * HID * 2);

    float* sum1 = meta + 0,   *sq1 = meta + 96;
    float* sum2 = meta + 192, *sq2 = meta + 288;
    float* bnA1 = meta + 384, *bnC1 = meta + 480;
    float* bnA2 = meta + 576, *bnC2 = meta + 672;

    const int EB = (NE + 255) / 256;
    const int VB = (NN + 255) / 256;
    k_init<<<VB, 256, 0, stream>>>(deg, meta);
    k_hist<<<EB, 256, 0, stream>>>(dst, deg, rank);
    k_scan1<<<SCAN_NB, 256, 0, stream>>>(deg, row_start, blksum, dinv);
    k_scan2<<<1, 512, 0, stream>>>(blksum, row_start);
    k_scan3<<<SCAN_NB, 256, 0, stream>>>(row_start, blksum);
    k_scatter<<<EB, 256, 0, stream>>>(src, dst, row_start, rank, dinv, ewt);

    const int GB = (NN + 127) / 128;  // 782 GEMM blocks
    const int AB = 2048;              // agg blocks: exactly 8 per CU

    // layer 1: z = x@W1 ; h1 = agg(z)+b1 (+stats)
    k_gemm<DIN, HID, false, float><<<GB, 256, 0, stream>>>(x, W1, bufA, nullptr, nullptr, NN);
    k_agg96<<<AB, 256, 0, stream>>>(bufA, bufB, b1, row_start, ewt, dinv, sum1, sq1);
    k_bncoef<<<1, 128, 0, stream>>>(sum1, sq1, g1, be1, bnA1, bnC1);

    // layer 2: z = relu(bn(h1))@W2 ; h2 = agg(z)+b2 (+stats)
    k_gemm<HID, HID, true, u16><<<GB, 256, 0, stream>>>(bufB, W2, bufA, bnA1, bnC1, NN);
    k_agg96<<<AB, 256, 0, stream>>>(bufA, bufB, b2, row_start, ewt, dinv, sum2, sq2);
    k_bncoef<<<1, 128, 0, stream>>>(sum2, sq2, g2, be2, bnA2, bnC2);

    // layer 3: z = relu(bn(h2))@W3 ; out = log_softmax(agg(z)+b3)
    k_gemm<HID, DOUT, true, u16><<<GB, 256, 0, stream>>>(bufB, W3, bufA, bnA2, bnC2, NN);
    k_agg32_lsm<<<AB, 256, 0, stream>>>(bufA, out, b3, row_start, ewt, dinv);

    (void)in_sizes; (void)n_in; (void)out_size; (void)ws_size;
}

// Round 8
// 427.822 us; speedup vs baseline: 2.1823x; 1.1327x over previous
//
#include <hip/hip_runtime.h>
#include <hip/hip_fp16.h>
#include <cstddef>

#define NN 100000
#define NE 800000
#define DIN 128
#define HID 96
#define DOUT 32
static constexpr float BN_EPS = 1e-5f;
#define SCAN_NB ((NN + 255) / 256)   // 391

typedef unsigned short u16;
typedef unsigned int u32;

__device__ __forceinline__ float b2f(u32 lo16) {
    union { u32 u; float f; } c; c.u = lo16 << 16; return c.f;
}
__device__ __forceinline__ u16 f2b(float f) {
    union { float f; u32 u; } c; c.f = f;
    return (u16)((c.u + 0x7FFFu + ((c.u >> 16) & 1u)) >> 16);
}
// packed edge: bits[31:15] = src (17b), bits[14:0] = fp16 weight (sign bit 0, w>0)
__device__ __forceinline__ u32 pack_edge(int s, float w) {
    __half h = __float2half(w);
    return ((u32)s << 15) | (u32)__half_as_ushort(h);
}
__device__ __forceinline__ int edge_src(u32 pk) { return (int)(pk >> 15); }
__device__ __forceinline__ float edge_wt(u32 pk) {
    return __half2float(__ushort_as_half((u16)(pk & 0x7FFFu)));
}

// ---------------------------------------------------------------- setup kernels

__global__ void k_init(int* __restrict__ deg) {
    int i = blockIdx.x * 256 + threadIdx.x;
    if (i < NN) deg[i] = 0;
}

// scan phase 1 + dinv fused
__global__ __launch_bounds__(256) void k_scan1(const int* __restrict__ deg,
                                               int* __restrict__ row_start,
                                               int* __restrict__ blksum,
                                               float* __restrict__ dinv) {
    __shared__ int lds[256];
    int t = threadIdx.x;
    int i = blockIdx.x * 256 + t;
    int v = (i < NN) ? deg[i] : 0;
    if (i < NN) dinv[i] = rsqrtf((float)(v + 1));  // +1 self-loop
    lds[t] = v;
    __syncthreads();
#pragma unroll
    for (int off = 1; off < 256; off <<= 1) {
        int add = (t >= off) ? lds[t - off] : 0;
        __syncthreads();
        lds[t] += add;
        __syncthreads();
    }
    if (i < NN) row_start[i] = lds[t] - v;  // exclusive
    if (t == 255) blksum[blockIdx.x] = lds[255];
}

// scans block sums; also zeroes BN-stat accumulators (needed before first agg96)
__global__ __launch_bounds__(512) void k_scan2(int* __restrict__ blksum,
                                               int* __restrict__ row_start,
                                               float* __restrict__ meta) {
    __shared__ int lds[512];
    int t = threadIdx.x;
    if (t < 384) meta[t] = 0.f;
    int v = (t < SCAN_NB) ? blksum[t] : 0;
    lds[t] = v;
    __syncthreads();
#pragma unroll
    for (int off = 1; off < 512; off <<= 1) {
        int add = (t >= off) ? lds[t - off] : 0;
        __syncthreads();
        lds[t] += add;
        __syncthreads();
    }
    if (t < SCAN_NB) blksum[t] = lds[t] - v;  // exclusive block offset
    if (t == 511) row_start[NN] = lds[511];   // grand total (= NE)
}

__global__ __launch_bounds__(256) void k_scan3(int* __restrict__ row_start,
                                               const int* __restrict__ blksum) {
    int i = blockIdx.x * 256 + threadIdx.x;
    if (i < NN) row_start[i] += blksum[blockIdx.x];
}

// atomic-free scatter: position = row_start[dst] + rank; 4 B packed payload
__global__ void k_scatter(const int* __restrict__ src, const int* __restrict__ dst,
                          const int* __restrict__ row_start,
                          const int* __restrict__ rank,
                          const float* __restrict__ dinv,
                          u32* __restrict__ ewt) {
    int e = blockIdx.x * blockDim.x + threadIdx.x;
    if (e < NE) {
        int d = dst[e];
        int p = row_start[d] + rank[e];
        int s = src[e];
        ewt[p] = pack_edge(s, dinv[s]);
    }
}

// ---------------------------------------------------------------- GEMM (fp32 vector)
// Z[M x ND](bf16) = f(X)[M x KD] @ W[KD x ND], f = optional relu(a*x+c) per K-channel.
// Xs transposed to [kk][row] (stride 132) -> xr via 2x ds_read_b128.
template <int KD, int ND, bool FUSE, typename XT>
__device__ __forceinline__ void gemm_body(int bid, const XT* __restrict__ X,
                                          const float* __restrict__ W,
                                          u16* __restrict__ Z,
                                          const float* __restrict__ bnA,
                                          const float* __restrict__ bnC, int M) {
    constexpr int BK = 32;
    constexpr int CT = 16;
    constexpr int CPT = ND / CT;   // 6 (ND=96) or 2 (ND=32)
    constexpr int RPT = 8;         // 16 row-threads * 8 = 128 rows
    constexpr int XS = 132;        // row stride in Xs (pad, 16B-aligned rows)
    __shared__ float Xs[BK * XS];
    __shared__ float Ws[BK * ND];
    __shared__ float As[KD], Cs[KD];

    int tid = threadIdx.x;
    if (FUSE && tid < KD) { As[tid] = bnA[tid]; Cs[tid] = bnC[tid]; }
    int row0 = bid * 128;
    int ct = tid % CT, rt = tid / CT;
    float acc[RPT][CPT];
#pragma unroll
    for (int r = 0; r < RPT; ++r)
#pragma unroll
        for (int c = 0; c < CPT; ++c) acc[r][c] = 0.f;

    for (int k0 = 0; k0 < KD; k0 += BK) {
        __syncthreads();
        if constexpr (sizeof(XT) == 4) {
            // fp32: float4/thread, 4 passes of 32 rows; write transposed
#pragma unroll
            for (int pass = 0; pass < 4; ++pass) {
                int r = pass * 32 + (tid >> 3);
                int kq = (tid & 7) * 4;
                int grow = row0 + r;
                float4 v = make_float4(0.f, 0.f, 0.f, 0.f);
                if (grow < M) v = *(const float4*)&X[(size_t)grow * KD + k0 + kq];
                if (FUSE) {
                    v.x = fmaxf(fmaf(As[k0 + kq + 0], v.x, Cs[k0 + kq + 0]), 0.f);
                    v.y = fmaxf(fmaf(As[k0 + kq + 1], v.y, Cs[k0 + kq + 1]), 0.f);
                    v.z = fmaxf(fmaf(As[k0 + kq + 2], v.z, Cs[k0 + kq + 2]), 0.f);
                    v.w = fmaxf(fmaf(As[k0 + kq + 3], v.w, Cs[k0 + kq + 3]), 0.f);
                }
                Xs[(kq + 0) * XS + r] = v.x;
                Xs[(kq + 1) * XS + r] = v.y;
                Xs[(kq + 2) * XS + r] = v.z;
                Xs[(kq + 3) * XS + r] = v.w;
            }
        } else {
            // bf16: uint4 = 8 elems/thread, 4 threads/row, 2 passes of 64 rows
#pragma unroll
            for (int pass = 0; pass < 2; ++pass) {
                int r = pass * 64 + (tid >> 2);
                int kq = (tid & 3) * 8;
                int grow = row0 + r;
                uint4 v = make_uint4(0, 0, 0, 0);
                if (grow < M) v = *(const uint4*)&X[(size_t)grow * KD + k0 + kq];
                u32 w[4] = {v.x, v.y, v.z, v.w};
#pragma unroll
                for (int q = 0; q < 4; ++q) {
                    float lo = b2f(w[q] & 0xFFFFu);
                    float hi = b2f(w[q] >> 16);
                    if (FUSE) {
                        lo = fmaxf(fmaf(As[k0 + kq + 2 * q + 0], lo, Cs[k0 + kq + 2 * q + 0]), 0.f);
                        hi = fmaxf(fmaf(As[k0 + kq + 2 * q + 1], hi, Cs[k0 + kq + 2 * q + 1]), 0.f);
                    }
                    Xs[(kq + 2 * q + 0) * XS + r] = lo;
                    Xs[(kq + 2 * q + 1) * XS + r] = hi;
                }
            }
        }
#pragma unroll
        for (int f = tid; f < BK * ND / 4; f += 256) {
            int kk = f / (ND / 4);
            int c4 = (f % (ND / 4)) * 4;
            *(float4*)&Ws[kk * ND + c4] = *(const float4*)&W[(size_t)(k0 + kk) * ND + c4];
        }
        __syncthreads();
#pragma unroll
        for (int kk = 0; kk < BK; ++kk) {
            float4 x0 = *(const float4*)&Xs[kk * XS + rt * 8];
            float4 x1 = *(const float4*)&Xs[kk * XS + rt * 8 + 4];
            float xr[RPT] = {x0.x, x0.y, x0.z, x0.w, x1.x, x1.y, x1.z, x1.w};
            float wc[CPT];
#pragma unroll
            for (int c = 0; c < CPT; ++c) wc[c] = Ws[kk * ND + ct * CPT + c];
#pragma unroll
            for (int r = 0; r < RPT; ++r)
#pragma unroll
                for (int c = 0; c < CPT; ++c) acc[r][c] = fmaf(xr[r], wc[c], acc[r][c]);
        }
    }
#pragma unroll
    for (int r = 0; r < RPT; ++r) {
        int grow = row0 + rt * RPT + r;
        if (grow < M) {
#pragma unroll
            for (int c = 0; c < CPT; c += 2) {
                u32 pk = (u32)f2b(acc[r][c]) | ((u32)f2b(acc[r][c + 1]) << 16);
                *(u32*)&Z[(size_t)grow * ND + ct * CPT + c] = pk;
            }
        }
    }
}

template <int KD, int ND, bool FUSE, typename XT>
__global__ __launch_bounds__(256) void k_gemm(const XT* __restrict__ X,
                                              const float* __restrict__ W,
                                              u16* __restrict__ Z,
                                              const float* __restrict__ bnA,
                                              const float* __restrict__ bnC, int M) {
    gemm_body<KD, ND, FUSE, XT>(blockIdx.x, X, W, Z, bnA, bnC, M);
}

// fused: blocks [0, gemm_blocks) do GEMM1; the rest do the edge histogram
__global__ __launch_bounds__(256) void k_gemm1_hist(const float* __restrict__ X,
                                                    const float* __restrict__ W,
                                                    u16* __restrict__ Z, int M,
                                                    int gemm_blocks,
                                                    const int* __restrict__ dst,
                                                    int* __restrict__ deg,
                                                    int* __restrict__ rank) {
    if ((int)blockIdx.x < gemm_blocks) {
        gemm_body<DIN, HID, false, float>(blockIdx.x, X, W, Z, nullptr, nullptr, M);
    } else {
        int e = ((int)blockIdx.x - gemm_blocks) * 256 + (int)threadIdx.x;
        if (e < NE) rank[e] = atomicAdd(&deg[dst[e]], 1);
    }
}

// ---------------------------------------------------------------- aggregation, 96ch (bf16)
// one wave per node; lane l<48 gathers the row's dword l. Two-chunk pipeline (16 in flight).
__global__ __launch_bounds__(256) void k_agg96(const u16* __restrict__ Z,
                                               u16* __restrict__ H,
                                               const float* __restrict__ bias,
                                               const int* __restrict__ row_start,
                                               const u32* __restrict__ ewt,
                                               const float* __restrict__ dinv,
                                               float* __restrict__ gsum,
                                               float* __restrict__ gsq) {
    __shared__ float ssum[96], ssq[96];
    int tid = threadIdx.x;
    if (tid < 96) { ssum[tid] = 0.f; ssq[tid] = 0.f; }
    __syncthreads();
    int wid = tid >> 6, lane = tid & 63;
    bool act = lane < 48;
    int l = act ? lane : 47;
    const u32* zu = (const u32*)Z;          // row stride 48 dwords
    float b0 = bias[2 * l], b1 = bias[2 * l + 1];
    float lsum0 = 0.f, lsq0 = 0.f, lsum1 = 0.f, lsq1 = 0.f;
    const int stride = gridDim.x * 4;

    int n = blockIdx.x * 4 + wid;
    int e0 = 0, e1 = 0;
    u32 pr = 0;
    if (n < NN) {
        e0 = row_start[n]; e1 = row_start[n + 1];
        if (e0 + lane < e1) pr = ewt[e0 + lane];
    }
    while (n < NN) {
        int n2 = n + stride;
        int e0n = 0, e1n = 0;
        if (n2 < NN) { e0n = row_start[n2]; e1n = row_start[n2 + 1]; }

        float dn = dinv[n];
        u32 uself = zu[(size_t)n * 48 + l];
        float a0a = dn * b2f(uself & 0xFFFFu);
        float a1a = dn * b2f(uself >> 16);
        float a0b = 0.f, a1b = 0.f;

        u32 plv = pr;

        u32 prn = 0;
        if (n2 < NN && e0n + lane < e1n) prn = ewt[e0n + lane];

        int m = e1 - e0;
        if (m <= 64) {
            int K = (m + 7) >> 3;
            u32 uA[8], uB[8];
            float wA[8], wB[8];
            {
#pragma unroll
                for (int q = 0; q < 8; ++q) {
                    bool v = q < m;
                    u32 pk = __shfl(plv, v ? q : 0);
                    wA[q] = v ? edge_wt(pk) : 0.f;
                    uA[q] = zu[(size_t)edge_src(pk) * 48 + l];
                }
            }
            for (int c = 0; c < K; ++c) {
                if ((c & 1) == 0) {
                    if (c + 1 < K) {
#pragma unroll
                        for (int q = 0; q < 8; ++q) {
                            int j = (c + 1) * 8 + q;
                            bool v = j < m;
                            u32 pk = __shfl(plv, v ? j : 0);
                            wB[q] = v ? edge_wt(pk) : 0.f;
                            uB[q] = zu[(size_t)edge_src(pk) * 48 + l];
                        }
                    }
#pragma unroll
                    for (int q = 0; q < 8; q += 2) {
                        a0a = fmaf(wA[q], b2f(uA[q] & 0xFFFFu), a0a);
                        a1a = fmaf(wA[q], b2f(uA[q] >> 16), a1a);
                        a0b = fmaf(wA[q + 1], b2f(uA[q + 1] & 0xFFFFu), a0b);
                        a1b = fmaf(wA[q + 1], b2f(uA[q + 1] >> 16), a1b);
                    }
                } else {
                    if (c + 1 < K) {
#pragma unroll
                        for (int q = 0; q < 8; ++q) {
                            int j = (c + 1) * 8 + q;
                            bool v = j < m;
                            u32 pk = __shfl(plv, v ? j : 0);
                            wA[q] = v ? edge_wt(pk) : 0.f;
                            uA[q] = zu[(size_t)edge_src(pk) * 48 + l];
                        }
                    }
#pragma unroll
                    for (int q = 0; q < 8; q += 2) {
                        a0a = fmaf(wB[q], b2f(uB[q] & 0xFFFFu), a0a);
                        a1a = fmaf(wB[q], b2f(uB[q] >> 16), a1a);
                        a0b = fmaf(wB[q + 1], b2f(uB[q + 1] & 0xFFFFu), a0b);
                        a1b = fmaf(wB[q + 1], b2f(uB[q + 1] >> 16), a1b);
                    }
                }
            }
        } else {
            // rare: deg > 64, windowed fallback
            u32 cw = plv;
            for (int eb = e0; eb < e1; eb += 64) {
                if (eb != e0) {
                    int idx = eb + lane;
                    cw = (idx < e1) ? ewt[idx] : 0;
                }
                int mm = e1 - eb; if (mm > 64) mm = 64;
                for (int j = 0; j < mm; ++j) {
                    u32 pk = __shfl(cw, j);
                    float w = edge_wt(pk);
                    u32 u = zu[(size_t)edge_src(pk) * 48 + l];
                    a0a = fmaf(w, b2f(u & 0xFFFFu), a0a);
                    a1a = fmaf(w, b2f(u >> 16), a1a);
                }
            }
        }
        float h0 = fmaf(dn, a0a + a0b, b0);
        float h1 = fmaf(dn, a1a + a1b, b1);
        if (act) {
            u32 pk = (u32)f2b(h0) | ((u32)f2b(h1) << 16);
            ((u32*)H)[(size_t)n * 48 + l] = pk;
            lsum0 += h0; lsq0 = fmaf(h0, h0, lsq0);
            lsum1 += h1; lsq1 = fmaf(h1, h1, lsq1);
        }
        n = n2; e0 = e0n; e1 = e1n; pr = prn;
    }
    if (act) {
        atomicAdd(&ssum[2 * l], lsum0); atomicAdd(&ssq[2 * l], lsq0);
        atomicAdd(&ssum[2 * l + 1], lsum1); atomicAdd(&ssq[2 * l + 1], lsq1);
    }
    __syncthreads();
    if (tid < 96) { atomicAdd(&gsum[tid], ssum[tid]); atomicAdd(&gsq[tid], ssq[tid]); }
}

__global__ void k_bncoef(const float* __restrict__ gsum, const float* __restrict__ gsq,
                         const float* __restrict__ g, const float* __restrict__ be,
                         float* __restrict__ bnA, float* __restrict__ bnC) {
    int c = threadIdx.x;
    if (c < 96) {
        float mean = gsum[c] * (1.f / NN);
        float var = gsq[c] * (1.f / NN) - mean * mean;
        float inv = rsqrtf(var + BN_EPS);
        float a = g[c] * inv;
        bnA[c] = a;
        bnC[c] = fmaf(-a, mean, be[c]);
    }
}

// ---------------------------------------------------------------- final agg + log_softmax
// 4 nodes per wave (16-lane groups). Full-window gather: all <=16 edges in flight.
__global__ __launch_bounds__(256) void k_agg32_lsm(const u16* __restrict__ Z,
                                                   float* __restrict__ Out,
                                                   const float* __restrict__ bias,
                                                   const int* __restrict__ row_start,
                                                   const u32* __restrict__ ewt,
                                                   const float* __restrict__ dinv) {
    int tid = threadIdx.x;
    int wid = tid >> 6, lane = tid & 63;
    int g = lane >> 4, sl = lane & 15;
    const u32* zu = (const u32*)Z;  // row stride 16 dwords
    float b0 = bias[2 * sl], b1 = bias[2 * sl + 1];
    int stride = gridDim.x * 16;
    for (int n0 = (blockIdx.x * 4 + wid) * 4; n0 < NN; n0 += stride) {
        int n = n0 + g;
        bool vn = n < NN;
        float dn = vn ? dinv[n] : 0.f;
        u32 uself = vn ? zu[(size_t)n * 16 + sl] : 0;
        float a0a = dn * b2f(uself & 0xFFFFu);
        float a1a = dn * b2f(uself >> 16);
        float a0b = 0.f, a1b = 0.f;
        int e0 = vn ? row_start[n] : 0, e1 = vn ? row_start[n + 1] : 0;
        for (int eb = e0; eb < e1; eb += 16) {
            int m = e1 - eb; if (m > 16) m = 16;
            int idx = eb + sl;
            u32 plv = (idx < e1) ? ewt[idx] : 0;
            u32 u_[16]; float w_[16];
#pragma unroll
            for (int q = 0; q < 16; ++q) {
                bool v = q < m;
                u32 pk = __shfl(plv, v ? q : 0, 16);
                w_[q] = v ? edge_wt(pk) : 0.f;
                u_[q] = zu[(size_t)edge_src(pk) * 16 + sl];
            }
#pragma unroll
            for (int q = 0; q < 16; q += 2) {
                a0a = fmaf(w_[q], b2f(u_[q] & 0xFFFFu), a0a);
                a1a = fmaf(w_[q], b2f(u_[q] >> 16), a1a);
                a0b = fmaf(w_[q + 1], b2f(u_[q + 1] & 0xFFFFu), a0b);
                a1b = fmaf(w_[q + 1], b2f(u_[q + 1] >> 16), a1b);
            }
        }
        float v0 = fmaf(dn, a0a + a0b, b0);
        float v1 = fmaf(dn, a1a + a1b, b1);
        float mx = fmaxf(v0, v1);
#pragma unroll
        for (int off = 8; off; off >>= 1) mx = fmaxf(mx, __shfl_xor(mx, off, 16));
        float ex = __expf(v0 - mx) + __expf(v1 - mx);
#pragma unroll
        for (int off = 8; off; off >>= 1) ex += __shfl_xor(ex, off, 16);
        float lse = mx + __logf(ex);
        if (vn) {
            float2 o = make_float2(v0 - lse, v1 - lse);
            *(float2*)&Out[(size_t)n * 32 + 2 * sl] = o;
        }
    }
}

// ---------------------------------------------------------------- launch

extern "C" void kernel_launch(void* const* d_in, const int* in_sizes, int n_in,
                              void* d_out, int out_size, void* d_ws, size_t ws_size,
                              hipStream_t stream) {
    const float* x  = (const float*)d_in[0];
    const int* ei   = (const int*)d_in[1];   // [2, NE]: src then dst
    const float* W1 = (const float*)d_in[2];
    const float* b1 = (const float*)d_in[3];
    const float* W2 = (const float*)d_in[4];
    const float* b2 = (const float*)d_in[5];
    const float* W3 = (const float*)d_in[6];
    const float* b3 = (const float*)d_in[7];
    const float* g1 = (const float*)d_in[8];
    const float* be1 = (const float*)d_in[9];
    const float* g2 = (const float*)d_in[10];
    const float* be2 = (const float*)d_in[11];
    float* out = (float*)d_out;

    const int* src = ei;
    const int* dst = ei + NE;

    char* p = (char*)d_ws;
    size_t off = 0;
    auto take = [&](size_t bytes) {
        char* r = p + off;
        off = (off + bytes + 255) & ~(size_t)255;
        return r;
    };
    float* dinv      = (float*)take(NN * 4);
    int*   deg       = (int*)take(NN * 4);
    int*   row_start = (int*)take((NN + 1) * 4);
    int*   blksum    = (int*)take(SCAN_NB * 4);
    int*   rank      = (int*)take((size_t)NE * 4);
    u32*   ewt       = (u32*)take((size_t)NE * 4);
    float* meta      = (float*)take(768 * 4);
    u16*   bufA      = (u16*)take((size_t)NN * HID * 2);
    u16*   bufB      = (u16*)take((size_t)NN * HID * 2);

    float* sum1 = meta + 0,   *sq1 = meta + 96;
    float* sum2 = meta + 192, *sq2 = meta + 288;
    float* bnA1 = meta + 384, *bnC1 = meta + 480;
    float* bnA2 = meta + 576, *bnC2 = meta + 672;

    const int EB = (NE + 255) / 256;   // 3125
    const int VB = (NN + 255) / 256;   // 391
    const int GB = (NN + 127) / 128;   // 782 GEMM blocks
    const int AB = 2048;               // agg blocks: 8 per CU

    k_init<<<VB, 256, 0, stream>>>(deg);
    // GEMM1 (independent of graph setup) fused with edge histogram
    k_gemm1_hist<<<GB + EB, 256, 0, stream>>>(x, W1, bufA, NN, GB, dst, deg, rank);
    k_scan1<<<SCAN_NB, 256, 0, stream>>>(deg, row_start, blksum, dinv);
    k_scan2<<<1, 512, 0, stream>>>(blksum, row_start, meta);
    k_scan3<<<SCAN_NB, 256, 0, stream>>>(row_start, blksum);
    k_scatter<<<EB, 256, 0, stream>>>(src, dst, row_start, rank, dinv, ewt);

    // layer 1 aggregation (z1 already in bufA)
    k_agg96<<<AB, 256, 0, stream>>>(bufA, bufB, b1, row_start, ewt, dinv, sum1, sq1);
    k_bncoef<<<1, 128, 0, stream>>>(sum1, sq1, g1, be1, bnA1, bnC1);

    // layer 2: z = relu(bn(h1))@W2 ; h2 = agg(z)+b2 (+stats)
    k_gemm<HID, HID, true, u16><<<GB, 256, 0, stream>>>(bufB, W2, bufA, bnA1, bnC1, NN);
    k_agg96<<<AB, 256, 0, stream>>>(bufA, bufB, b2, row_start, ewt, dinv, sum2, sq2);
    k_bncoef<<<1, 128, 0, stream>>>(sum2, sq2, g2, be2, bnA2, bnC2);

    // layer 3: z = relu(bn(h2))@W3 ; out = log_softmax(agg(z)+b3)
    k_gemm<HID, DOUT, true, u16><<<GB, 256, 0, stream>>>(bufB, W3, bufA, bnA2, bnC2, NN);
    k_agg32_lsm<<<AB, 256, 0, stream>>>(bufA, out, b3, row_start, ewt, dinv);

    (void)in_sizes; (void)n_in; (void)out_size; (void)ws_size;
}